// Round 3
// baseline (454.538 us; speedup 1.0000x reference)
//
#include <hip/hip_runtime.h>
#include <hip/hip_fp16.h>

// ConvSE3: B=1, N=512, J=48, M=16, MID=128, pairs (di,do) in {0,1}^2.
// Pipeline (per pair p, interleaved to bound workspace):
//   k1 : per-edge radial MLP -> h2 (fp16, ws window)
//   k2a: per-n: gather, Em[j,q]=m_j*sum_v basis*xg, S[c,q]=sum_j h2aug[j,c]*Em[j,q] -> ws (fp32)
//   k2b: out[(n,u),o] += sum_{c,k} S[(n,u),(c,k)] * w3[c,(o,k)] / denom  (w3 staged in LDS,
//        amortized over 128 rows/block -- kills the per-n w3 re-read that bound R2's k2)
// k0 : LN1 analytic stats, mask-dtype probe, denomInv, self-interaction init of out.

#define EPSV 1e-5f
constexpr int NN  = 512;
constexpr int JJ  = 48;
constexpr int EE  = NN * JJ;   // 24576 edges

// ---------------------------------------------------------------- k0
__global__ __launch_bounds__(256) void k0_prep(
    const float* __restrict__ w1, const float* __restrict__ b1,
    const void* __restrict__ nmask,
    const float* __restrict__ x0, const float* __restrict__ x1,
    const float* __restrict__ ks0, const float* __restrict__ ks1,
    float* __restrict__ dInv, float* __restrict__ out, float* __restrict__ stats)
{
    const int t = threadIdx.x;
    if (blockIdx.x == 0) {
        // LN1 analytic stats per pair: mu = d*wbar+bbar ; var = d^2*Cw + 2d*Cwb + Cb
        const int p = t >> 6, lane = t & 63;
        const float w0 = w1[p*128 + lane],       b0 = b1[p*128 + lane];
        const float w1v = w1[p*128 + 64 + lane], b1v = b1[p*128 + 64 + lane];
        float sw = w0 + w1v, sb = b0 + b1v;
        float sww = w0*w0 + w1v*w1v, swb = w0*b0 + w1v*b1v, sbb = b0*b0 + b1v*b1v;
        for (int off = 32; off > 0; off >>= 1) {
            sw  += __shfl_down(sw, off);  sb  += __shfl_down(sb, off);
            sww += __shfl_down(sww, off); swb += __shfl_down(swb, off);
            sbb += __shfl_down(sbb, off);
        }
        if (lane == 0) {
            const float wbar = sw*(1.f/128.f), bbar = sb*(1.f/128.f);
            stats[p*8+0] = wbar; stats[p*8+1] = bbar;
            stats[p*8+2] = sww*(1.f/128.f) - wbar*wbar;
            stats[p*8+3] = swb*(1.f/128.f) - wbar*bbar;
            stats[p*8+4] = sbb*(1.f/128.f) - bbar*bbar;
        }
        return;
    }
    if (blockIdx.x == 1) {
        // mask dtype probe: if int32, all words are 0/1; packed uint8 bools produce >1 words.
        __shared__ int flag;
        if (t == 0) flag = 0;
        __syncthreads();
        const int* m32 = (const int*)nmask;
        int bad = 0;
        for (int i = t; i < EE/4; i += 256) if ((unsigned)m32[i] > 1u) bad = 1;
        if (bad) flag = 1;
        __syncthreads();
        const int useU8 = flag;
        if (t == 0) stats[30] = useU8 ? 1.f : 0.f;
        for (int n = t; n < NN; n += 256) {
            float s = 0.f;
            if (useU8) {
                const unsigned char* m8 = (const unsigned char*)nmask;
                for (int j = 0; j < JJ; ++j) s += m8[n*JJ + j] ? 1.f : 0.f;
            } else {
                for (int j = 0; j < JJ; ++j) s += m32[n*JJ + j] ? 1.f : 0.f;
            }
            dInv[n] = 1.f / s;
        }
        return;
    }
    // self-interaction init: out[n,o,d]
    const int gid = (blockIdx.x - 2) * 256 + t;
    if (gid >= NN*16*4) return;
    const int d = gid & 3, o = (gid >> 2) & 15, n = gid >> 6;
    float acc = 0.f;
    if (d == 0) {
        #pragma unroll
        for (int i = 0; i < 16; ++i) acc += ks0[o*16+i] * x0[n*16+i];
    } else {
        const int u = d - 1;
        #pragma unroll
        for (int i = 0; i < 16; ++i) acc += ks1[o*16+i] * x1[(n*16+i)*3 + u];
    }
    out[gid] = acc;
}

// ---------------------------------------------------------------- k1: radial MLP (one pair per launch)
__global__ __launch_bounds__(128) void k1_mlp(
    const int p,
    const float* __restrict__ rel,
    const float* __restrict__ w1, const float* __restrict__ b1,
    const float* __restrict__ g1, const float* __restrict__ be1,
    const float* __restrict__ w2, const float* __restrict__ b2,
    const float* __restrict__ g2, const float* __restrict__ be2,
    const float* __restrict__ stats, __half* __restrict__ h2out)
{
    const int e0 = blockIdx.x * 64;
    const int t  = threadIdx.x;
    __shared__ __align__(16) float h1T[128*68];   // [cin][edge], stride 68; overlaid below after GEMM
    __shared__ float dsh[64];
    float* redS = h1T;            // 64*16
    float* redQ = h1T + 1024;     // 64*16
    float* muA  = h1T + 2048;     // 64
    float* rsA  = h1T + 2176;     // 64

    if (t < 64) dsh[t] = rel[e0 + t];
    __syncthreads();

    {   // h1 = relu(LN(d*w1+b1)) via analytic LN stats; thread t = cin
        const float w  = w1[p*128 + t], b  = b1[p*128 + t];
        const float g  = g1[p*128 + t], be = be1[p*128 + t];
        const float wbar = stats[p*8+0], bbar = stats[p*8+1];
        const float Cw = stats[p*8+2], Cwb = stats[p*8+3], Cb = stats[p*8+4];
        #pragma unroll 4
        for (int e = 0; e < 64; ++e) {
            const float d   = dsh[e];
            const float mu  = fmaf(d, wbar, bbar);
            const float var = fmaf(d*d, Cw, fmaf(2.f*d, Cwb, Cb));
            const float y   = fmaf((fmaf(d, w, b) - mu) * rsqrtf(var + EPSV), g, be);
            h1T[t*68 + e] = fmaxf(y, 0.f);
        }
    }
    __syncthreads();

    // h2pre = h1 @ w2 + b2 ; 8 edges x 8 couts per thread
    const int eb = (t & 7) * 8;
    const int cb = (t >> 3) * 8;
    float acc[8][8];
    #pragma unroll
    for (int a = 0; a < 8; ++a)
        #pragma unroll
        for (int c = 0; c < 8; ++c) acc[a][c] = 0.f;

    const float* __restrict__ w2p = w2 + p*16384;
    for (int k = 0; k < 128; ++k) {
        const float4 a0 = *(const float4*)(h1T + k*68 + eb);
        const float4 a1 = *(const float4*)(h1T + k*68 + eb + 4);
        const float4 v0 = *(const float4*)(w2p + k*128 + cb);
        const float4 v1 = *(const float4*)(w2p + k*128 + cb + 4);
        const float av[8] = {a0.x,a0.y,a0.z,a0.w,a1.x,a1.y,a1.z,a1.w};
        const float wv[8] = {v0.x,v0.y,v0.z,v0.w,v1.x,v1.y,v1.z,v1.w};
        #pragma unroll
        for (int ee = 0; ee < 8; ++ee)
            #pragma unroll
            for (int cc = 0; cc < 8; ++cc)
                acc[ee][cc] = fmaf(av[ee], wv[cc], acc[ee][cc]);
    }
    {
        const float4 bv0 = *(const float4*)(b2 + p*128 + cb);
        const float4 bv1 = *(const float4*)(b2 + p*128 + cb + 4);
        const float bv[8] = {bv0.x,bv0.y,bv0.z,bv0.w,bv1.x,bv1.y,bv1.z,bv1.w};
        #pragma unroll
        for (int ee = 0; ee < 8; ++ee)
            #pragma unroll
            for (int cc = 0; cc < 8; ++cc) acc[ee][cc] += bv[cc];
    }
    __syncthreads();   // all h1T reads done before overlaying red arrays
    #pragma unroll
    for (int ee = 0; ee < 8; ++ee) {
        float s = 0.f, q = 0.f;
        #pragma unroll
        for (int cc = 0; cc < 8; ++cc) { s += acc[ee][cc]; q += acc[ee][cc]*acc[ee][cc]; }
        redS[(eb+ee)*16 + (t>>3)] = s;
        redQ[(eb+ee)*16 + (t>>3)] = q;
    }
    __syncthreads();
    if (t < 64) {
        float s = 0.f, q = 0.f;
        #pragma unroll
        for (int k2 = 0; k2 < 16; ++k2) { s += redS[t*16+k2]; q += redQ[t*16+k2]; }
        const float mu  = s * (1.f/128.f);
        const float var = fmaf(-mu, mu, q * (1.f/128.f));
        muA[t] = mu;
        rsA[t] = rsqrtf(var + EPSV);
    }
    __syncthreads();
    {
        const float4 gv0 = *(const float4*)(g2 + p*128 + cb);
        const float4 gv1 = *(const float4*)(g2 + p*128 + cb + 4);
        const float4 hv0 = *(const float4*)(be2 + p*128 + cb);
        const float4 hv1 = *(const float4*)(be2 + p*128 + cb + 4);
        const float gv[8]  = {gv0.x,gv0.y,gv0.z,gv0.w,gv1.x,gv1.y,gv1.z,gv1.w};
        const float bev[8] = {hv0.x,hv0.y,hv0.z,hv0.w,hv1.x,hv1.y,hv1.z,hv1.w};
        #pragma unroll
        for (int ee = 0; ee < 8; ++ee) {
            const float mu = muA[eb+ee], rs = rsA[eb+ee];
            union { float4 f; __half h[8]; } u;
            #pragma unroll
            for (int cc = 0; cc < 8; ++cc)
                u.h[cc] = __float2half(fmaxf(fmaf((acc[ee][cc] - mu) * rs, gv[cc], bev[cc]), 0.f));
            *(float4*)(h2out + (size_t)(e0 + eb + ee) * 128 + cb) = u.f;
        }
    }
}

// ---------------------------------------------------------------- k2a: per-n Em + S-GEMM -> Sws
template<int DI, int DO>
__global__ __launch_bounds__(256) void k2a(
    const float* __restrict__ xsrc,
    const int* __restrict__ nidx,
    const void* __restrict__ nmaskv,
    const float* __restrict__ basis,
    const __half* __restrict__ h2w,
    const float* __restrict__ stats,
    float* __restrict__ Sws)
{
    constexpr int V  = 2*DI + 1;
    constexpr int U  = 2*DO + 1;
    constexpr int F  = 2*(DI < DO ? DI : DO) + 1;
    constexpr int KF = 16*F;
    constexpr int Q  = 16*U*F;          // q = u*KF + (i*F+f)
    constexpr int BP = U*V*F;
    constexpr int XW = 16*V;
    constexpr int KTOT = 129*KF;
    constexpr int TC = (U == 3) ? 4 : 2;
    constexpr int CT = 128/TC + 1;      // c0 = ct*TC covers 0..128
    constexpr int K4 = KF/4;

    const int n = blockIdx.x;
    const int t = threadIdx.x;

    __shared__ __align__(16) float Em[JJ*Q];
    __shared__ __align__(16) float Breg[JJ*XW + JJ*BP];
    __shared__ __align__(16) float h2L[JJ*132];   // cols 0..127 h2, col 128 = 1 (b3 row), 129..131 = 0
    __shared__ int   idxL[JJ];
    __shared__ float mjf[JJ];

    float* xg   = Breg;
    float* basL = Breg + JJ*XW;

    if (t < JJ) {
        idxL[t] = nidx[n*JJ + t];
        const int useU8 = (stats[30] != 0.f);
        const int mv = useU8 ? (int)((const unsigned char*)nmaskv)[n*JJ + t]
                             : ((const int*)nmaskv)[n*JJ + t];
        mjf[t] = mv ? 1.f : 0.f;
    }
    __syncthreads();

    for (int e = t; e < JJ*XW; e += 256) {
        const int j = e / XW, r = e - j*XW;
        xg[e] = xsrc[idxL[j]*XW + r];
    }
    for (int e = t; e < JJ*BP; e += 256)
        basL[e] = basis[n*JJ*BP + e];
    for (int e = t; e < JJ*128; e += 256) {
        const int j = e >> 7, c = e & 127;
        h2L[j*132 + c] = __half2float(h2w[(size_t)(n*JJ + j)*128 + c]);
    }
    if (t < JJ) {
        h2L[t*132 + 128] = 1.f;
        h2L[t*132 + 129] = 0.f; h2L[t*132 + 130] = 0.f; h2L[t*132 + 131] = 0.f;
    }
    __syncthreads();

    // Em[j][u*KF + i*F + f] = m_j * sum_v basis[j][(u*V+v)*F+f] * xg[j][i*V+v]
    for (int e = t; e < JJ*Q; e += 256) {
        const int j = e / Q, q = e - j*Q;
        const int u = q / KF, k = q - u*KF, i = k / F, f = k - i*F;
        float a = 0.f;
        #pragma unroll
        for (int v = 0; v < V; ++v)
            a = fmaf(basL[j*BP + (u*V + v)*F + f], xg[j*XW + i*V + v], a);
        Em[e] = mjf[j] * a;
    }
    __syncthreads();

    // S[c, u*KF+k] = sum_j h2aug[j,c] * Em[j, u*KF+k]  -> Sws[(n*U+u)*KTOT + c*KF + k]
    for (int task = t; task < CT*K4; task += 256) {
        const int ct = task / K4, k4 = task - ct*K4;
        const int c0 = ct*TC, k0 = k4*4;
        float sacc[TC][U][4];
        #pragma unroll
        for (int a = 0; a < TC; ++a)
            #pragma unroll
            for (int b = 0; b < U; ++b)
                #pragma unroll
                for (int c = 0; c < 4; ++c) sacc[a][b][c] = 0.f;

        for (int j = 0; j < JJ; ++j) {
            float hv[TC];
            if constexpr (TC == 4) {
                const float4 h = *(const float4*)(h2L + j*132 + c0);
                hv[0]=h.x; hv[1]=h.y; hv[2]=h.z; hv[3]=h.w;
            } else {
                const float2 h = *(const float2*)(h2L + j*132 + c0);
                hv[0]=h.x; hv[1]=h.y;
            }
            #pragma unroll
            for (int u = 0; u < U; ++u) {
                const float4 e = *(const float4*)(Em + j*Q + u*KF + k0);
                #pragma unroll
                for (int cc = 0; cc < TC; ++cc) {
                    sacc[cc][u][0] = fmaf(hv[cc], e.x, sacc[cc][u][0]);
                    sacc[cc][u][1] = fmaf(hv[cc], e.y, sacc[cc][u][1]);
                    sacc[cc][u][2] = fmaf(hv[cc], e.z, sacc[cc][u][2]);
                    sacc[cc][u][3] = fmaf(hv[cc], e.w, sacc[cc][u][3]);
                }
            }
        }
        #pragma unroll
        for (int cc = 0; cc < TC; ++cc) {
            if (c0 + cc > 128) continue;
            #pragma unroll
            for (int u = 0; u < U; ++u) {
                *(float4*)(Sws + (size_t)(n*U + u)*KTOT + (c0+cc)*KF + k0) =
                    make_float4(sacc[cc][u][0], sacc[cc][u][1], sacc[cc][u][2], sacc[cc][u][3]);
            }
        }
    }
}

// ---------------------------------------------------------------- k2b: out += w3^T * S (n-amortized)
template<int DI, int DO>
__global__ __launch_bounds__(256) void k2b(
    const float* __restrict__ w3, const float* __restrict__ b3,
    const float* __restrict__ Sws, const float* __restrict__ dInv,
    float* __restrict__ out)
{
    constexpr int U  = 2*DO + 1;
    constexpr int F  = 2*(DI < DO ? DI : DO) + 1;
    constexpr int KF = 16*F;
    constexpr int KTOT = 129*KF;
    constexpr int K4 = KF/4;
    constexpr int W3ROW = 16*KF;

    __shared__ __align__(16) float w3L[4*W3ROW];

    const int m0 = blockIdx.x * 128;
    const int c0 = blockIdx.y * 4;
    const int NC = (129 - c0) < 4 ? (129 - c0) : 4;
    const int t  = threadIdx.x;

    for (int e = t; e < NC*W3ROW; e += 256) {
        const int c = e / W3ROW, r = e - c*W3ROW;
        w3L[e] = (c0 + c < 128) ? w3[(size_t)(c0+c)*W3ROW + r] : b3[r];
    }
    __syncthreads();

    const int rg = t >> 3, ks = t & 7;
    const int r0 = m0 + rg*4;
    float acc[4][16];
    #pragma unroll
    for (int a = 0; a < 4; ++a)
        #pragma unroll
        for (int o = 0; o < 16; ++o) acc[a][o] = 0.f;

    for (int pi = ks; pi < NC*K4; pi += 8) {
        const int c = pi / K4, k4 = pi - c*K4;
        const size_t off = (size_t)(c0 + c)*KF + k4*4;
        float4 a[4];
        #pragma unroll
        for (int rr = 0; rr < 4; ++rr)
            a[rr] = *(const float4*)(Sws + (size_t)(r0 + rr)*KTOT + off);
        const float* wb = w3L + c*W3ROW + k4*4;
        #pragma unroll
        for (int o = 0; o < 16; ++o) {
            const float4 w = *(const float4*)(wb + o*KF);
            #pragma unroll
            for (int rr = 0; rr < 4; ++rr)
                acc[rr][o] += a[rr].x*w.x + a[rr].y*w.y + a[rr].z*w.z + a[rr].w*w.w;
        }
    }
    #pragma unroll
    for (int m = 1; m < 8; m <<= 1)
        #pragma unroll
        for (int rr = 0; rr < 4; ++rr)
            #pragma unroll
            for (int o = 0; o < 16; ++o)
                acc[rr][o] += __shfl_xor(acc[rr][o], m);

    if (ks == 0) {
        #pragma unroll
        for (int rr = 0; rr < 4; ++rr) {
            const int row = r0 + rr;
            const int nn = row / U, u = row - nn*U;
            const float d = dInv[nn];
            #pragma unroll
            for (int o = 0; o < 16; ++o)
                atomicAdd(out + (nn*16 + o)*4 + (DO == 0 ? 0 : 1 + u), acc[rr][o]*d);
        }
    }
}

// ---------------------------------------------------------------- launch
extern "C" void kernel_launch(void* const* d_in, const int* in_sizes, int n_in,
                              void* d_out, int out_size, void* d_ws, size_t ws_size,
                              hipStream_t stream)
{
    const float* x0    = (const float*)d_in[0];
    const float* x1    = (const float*)d_in[1];
    const float* rel   = (const float*)d_in[2];
    const int*   nidx  = (const int*)d_in[3];
    const void*  nmask = d_in[4];
    const float* basis[4] = {(const float*)d_in[5], (const float*)d_in[6],
                             (const float*)d_in[7], (const float*)d_in[8]};
    const float* w1  = (const float*)d_in[9];
    const float* b1  = (const float*)d_in[10];
    const float* g1  = (const float*)d_in[11];
    const float* be1 = (const float*)d_in[12];
    const float* w2  = (const float*)d_in[13];
    const float* b2  = (const float*)d_in[14];
    const float* g2  = (const float*)d_in[15];
    const float* be2 = (const float*)d_in[16];
    const float* w3a[4] = {(const float*)d_in[17], (const float*)d_in[19],
                           (const float*)d_in[21], (const float*)d_in[23]};
    const float* b3a[4] = {(const float*)d_in[18], (const float*)d_in[20],
                           (const float*)d_in[22], (const float*)d_in[24]};
    const float* ks0 = (const float*)d_in[25];
    const float* ks1 = (const float*)d_in[26];
    float* out = (float*)d_out;

    // ws layout: [0, 38.1MB) S ; [40MB, 46.3MB) h2 fp16 window ; [47MB) dInv + stats
    float*  Sws   = (float*)d_ws;
    __half* h2w   = (__half*)((char*)d_ws + (40u << 20));
    float*  dInv  = (float*)((char*)d_ws + (47u << 20));
    float*  stats = dInv + 1024;

    k0_prep<<<131, 256, 0, stream>>>(w1, b1, nmask, x0, x1, ks0, ks1, dInv, out, stats);

    // pair 0: (0,0)
    k1_mlp<<<384, 128, 0, stream>>>(0, rel, w1, b1, g1, be1, w2, b2, g2, be2, stats, h2w);
    k2a<0,0><<<NN, 256, 0, stream>>>(x0, nidx, nmask, basis[0], h2w, stats, Sws);
    k2b<0,0><<<dim3(512*1/128, 33), 256, 0, stream>>>(w3a[0], b3a[0], Sws, dInv, out);
    // pair 1: (0,1)
    k1_mlp<<<384, 128, 0, stream>>>(1, rel, w1, b1, g1, be1, w2, b2, g2, be2, stats, h2w);
    k2a<0,1><<<NN, 256, 0, stream>>>(x0, nidx, nmask, basis[1], h2w, stats, Sws);
    k2b<0,1><<<dim3(512*3/128, 33), 256, 0, stream>>>(w3a[1], b3a[1], Sws, dInv, out);
    // pair 2: (1,0)
    k1_mlp<<<384, 128, 0, stream>>>(2, rel, w1, b1, g1, be1, w2, b2, g2, be2, stats, h2w);
    k2a<1,0><<<NN, 256, 0, stream>>>(x1, nidx, nmask, basis[2], h2w, stats, Sws);
    k2b<1,0><<<dim3(512*1/128, 33), 256, 0, stream>>>(w3a[2], b3a[2], Sws, dInv, out);
    // pair 3: (1,1)
    k1_mlp<<<384, 128, 0, stream>>>(3, rel, w1, b1, g1, be1, w2, b2, g2, be2, stats, h2w);
    k2a<1,1><<<NN, 256, 0, stream>>>(x1, nidx, nmask, basis[3], h2w, stats, Sws);
    k2b<1,1><<<dim3(512*3/128, 33), 256, 0, stream>>>(w3a[3], b3a[3], Sws, dInv, out);
}

// Round 4
// 364.048 us; speedup vs baseline: 1.2486x; 1.2486x over previous
//
#include <hip/hip_runtime.h>
#include <hip/hip_fp16.h>

// ConvSE3: B=1, N=512, J=48, M=16, MID=128, pairs (di,do) in {0,1}^2.
//   k0 : LN1 analytic stats, mask probe, dInv, self-interaction init, w3T transpose (fp16)
//   k1 : per-edge radial MLP -> h2 (fp16)
//   k2a: per-n: Em[j,q]=m_j*sum_v basis*xg ; S[c,q]=sum_j h2aug[j,c]*Em[j,q] -> ws (fp16)
//   k2b: ONE dispatch, all pairs: out[row,o] += dot(S[row,:], w3T[o,:]) * dInv  (fdot2)
// R4: killed R3's k2b atomic storm (33 c-blocks x same address, WRITE 25MB) by fusing all c
// per lane; S+w3T fp16 halves S traffic; v_dot2_f32_f16 inner loop.

#define EPSV 1e-5f
constexpr int NN  = 512;
constexpr int JJ  = 48;
constexpr int EE  = NN * JJ;   // 24576 edges

// ws layout (bytes):
//   [0)            S fp16, pair offsets (elems): s00=0  s01=1056768  s10=4227072  s11=5283840
//   [29589504)     w3T fp16 [16][CK] per pair, offsets (elems): 0 / 33024 / 66048 / 99072
//   [29985792)     stats (32 f32)   [29985920) dInv (512 f32)
//   [29987968)     h2 fp16: merged = 4 x 3145728 elems (ends 55153792); windowed = 1 window
constexpr size_t SOFF[4]  = {0, 1056768, 4227072, 5283840};
constexpr size_t WTOFF[4] = {0, 33024, 66048, 99072};
constexpr size_t WT_BYTE   = 29589504;
constexpr size_t ST_BYTE   = 29985792;
constexpr size_t DI_BYTE   = 29985920;
constexpr size_t H2_BYTE   = 29987968;
constexpr size_t H2_STRIDE = 3145728;      // elems per pair

typedef _Float16 f16_t;
typedef __attribute__((ext_vector_type(2))) _Float16 h2v;

// ---------------------------------------------------------------- k0
__global__ __launch_bounds__(256) void k0_prep(
    const float* __restrict__ w1, const float* __restrict__ b1,
    const void* __restrict__ nmask,
    const float* __restrict__ x0, const float* __restrict__ x1,
    const float* __restrict__ ks0, const float* __restrict__ ks1,
    const float* __restrict__ w3_00, const float* __restrict__ b3_00,
    const float* __restrict__ w3_01, const float* __restrict__ b3_01,
    const float* __restrict__ w3_10, const float* __restrict__ b3_10,
    const float* __restrict__ w3_11, const float* __restrict__ b3_11,
    float* __restrict__ dInv, float* __restrict__ out, float* __restrict__ stats,
    __half* __restrict__ WT2)
{
    const int t = threadIdx.x;
    if (blockIdx.x == 0) {
        const int p = t >> 6, lane = t & 63;
        const float w0 = w1[p*128 + lane],       b0 = b1[p*128 + lane];
        const float w1v = w1[p*128 + 64 + lane], b1v = b1[p*128 + 64 + lane];
        float sw = w0 + w1v, sb = b0 + b1v;
        float sww = w0*w0 + w1v*w1v, swb = w0*b0 + w1v*b1v, sbb = b0*b0 + b1v*b1v;
        for (int off = 32; off > 0; off >>= 1) {
            sw  += __shfl_down(sw, off);  sb  += __shfl_down(sb, off);
            sww += __shfl_down(sww, off); swb += __shfl_down(swb, off);
            sbb += __shfl_down(sbb, off);
        }
        if (lane == 0) {
            const float wbar = sw*(1.f/128.f), bbar = sb*(1.f/128.f);
            stats[p*8+0] = wbar; stats[p*8+1] = bbar;
            stats[p*8+2] = sww*(1.f/128.f) - wbar*wbar;
            stats[p*8+3] = swb*(1.f/128.f) - wbar*bbar;
            stats[p*8+4] = sbb*(1.f/128.f) - bbar*bbar;
        }
        return;
    }
    if (blockIdx.x == 1) {
        __shared__ int flag;
        if (t == 0) flag = 0;
        __syncthreads();
        const int* m32 = (const int*)nmask;
        int bad = 0;
        for (int i = t; i < EE/4; i += 256) if ((unsigned)m32[i] > 1u) bad = 1;
        if (bad) flag = 1;
        __syncthreads();
        const int useU8 = flag;
        if (t == 0) stats[30] = useU8 ? 1.f : 0.f;
        for (int n = t; n < NN; n += 256) {
            float s = 0.f;
            if (useU8) {
                const unsigned char* m8 = (const unsigned char*)nmask;
                for (int j = 0; j < JJ; ++j) s += m8[n*JJ + j] ? 1.f : 0.f;
            } else {
                for (int j = 0; j < JJ; ++j) s += m32[n*JJ + j] ? 1.f : 0.f;
            }
            dInv[n] = 1.f / s;
        }
        return;
    }
    if (blockIdx.x < 130) {
        // self-interaction init
        const int gid = (blockIdx.x - 2) * 256 + t;
        const int d = gid & 3, o = (gid >> 2) & 15, n = gid >> 6;
        float acc = 0.f;
        if (d == 0) {
            #pragma unroll
            for (int i = 0; i < 16; ++i) acc += ks0[o*16+i] * x0[n*16+i];
        } else {
            const int u = d - 1;
            #pragma unroll
            for (int i = 0; i < 16; ++i) acc += ks1[o*16+i] * x1[(n*16+i)*3 + u];
        }
        out[gid] = acc;
        return;
    }
    // w3T transpose: WT2[p][o*CK + ck] = (c<128 ? w3[c, o*KF+k] : b3[o*KF+k]), ck=c*KF+k
    const int gid = (blockIdx.x - 130) * 256 + t;   // [0, 198144)
    int p, base;
    if      (gid < 33024)  { p = 0; base = 0; }
    else if (gid < 66048)  { p = 1; base = 33024; }
    else if (gid < 99072)  { p = 2; base = 66048; }
    else                   { p = 3; base = 99072; }
    const int KF = (p == 3) ? 48 : 16;
    const int CK = 129*KF;
    const int e = gid - base;
    const int o = e / CK, ck = e - o*CK;
    const int c = ck / KF, k = ck - c*KF;
    const float* w3 = (p==0) ? w3_00 : (p==1) ? w3_01 : (p==2) ? w3_10 : w3_11;
    const float* b3 = (p==0) ? b3_00 : (p==1) ? b3_01 : (p==2) ? b3_10 : b3_11;
    const float v = (c < 128) ? w3[(size_t)c*(16*KF) + o*KF + k] : b3[o*KF + k];
    WT2[base + (size_t)o*CK + ck] = __float2half(v);
}

// ---------------------------------------------------------------- k1: radial MLP
__global__ __launch_bounds__(128) void k1_mlp(
    const int pfix,
    const float* __restrict__ rel,
    const float* __restrict__ w1, const float* __restrict__ b1,
    const float* __restrict__ g1, const float* __restrict__ be1,
    const float* __restrict__ w2, const float* __restrict__ b2,
    const float* __restrict__ g2, const float* __restrict__ be2,
    const float* __restrict__ stats, __half* __restrict__ h2base, const size_t h2stride)
{
    const int p  = (pfix < 0) ? blockIdx.y : pfix;
    __half* h2out = h2base + (size_t)((pfix < 0) ? blockIdx.y : 0) * h2stride;
    const int e0 = blockIdx.x * 64;
    const int t  = threadIdx.x;
    __shared__ __align__(16) float h1T[128*68];
    __shared__ float dsh[64];
    float* redS = h1T;            // overlaid after GEMM reads complete
    float* redQ = h1T + 1024;
    float* muA  = h1T + 2048;
    float* rsA  = h1T + 2176;

    if (t < 64) dsh[t] = rel[e0 + t];
    __syncthreads();

    {   // h1 = relu(LN(d*w1+b1)) via analytic LN stats; thread t = cin
        const float w  = w1[p*128 + t], b  = b1[p*128 + t];
        const float g  = g1[p*128 + t], be = be1[p*128 + t];
        const float wbar = stats[p*8+0], bbar = stats[p*8+1];
        const float Cw = stats[p*8+2], Cwb = stats[p*8+3], Cb = stats[p*8+4];
        #pragma unroll 4
        for (int e = 0; e < 64; ++e) {
            const float d   = dsh[e];
            const float mu  = fmaf(d, wbar, bbar);
            const float var = fmaf(d*d, Cw, fmaf(2.f*d, Cwb, Cb));
            const float y   = fmaf((fmaf(d, w, b) - mu) * rsqrtf(var + EPSV), g, be);
            h1T[t*68 + e] = fmaxf(y, 0.f);
        }
    }
    __syncthreads();

    const int eb = (t & 7) * 8;
    const int cb = (t >> 3) * 8;
    float acc[8][8];
    #pragma unroll
    for (int a = 0; a < 8; ++a)
        #pragma unroll
        for (int c = 0; c < 8; ++c) acc[a][c] = 0.f;

    const float* __restrict__ w2p = w2 + p*16384;
    for (int k = 0; k < 128; ++k) {
        const float4 a0 = *(const float4*)(h1T + k*68 + eb);
        const float4 a1 = *(const float4*)(h1T + k*68 + eb + 4);
        const float4 v0 = *(const float4*)(w2p + k*128 + cb);
        const float4 v1 = *(const float4*)(w2p + k*128 + cb + 4);
        const float av[8] = {a0.x,a0.y,a0.z,a0.w,a1.x,a1.y,a1.z,a1.w};
        const float wv[8] = {v0.x,v0.y,v0.z,v0.w,v1.x,v1.y,v1.z,v1.w};
        #pragma unroll
        for (int ee = 0; ee < 8; ++ee)
            #pragma unroll
            for (int cc = 0; cc < 8; ++cc)
                acc[ee][cc] = fmaf(av[ee], wv[cc], acc[ee][cc]);
    }
    {
        const float4 bv0 = *(const float4*)(b2 + p*128 + cb);
        const float4 bv1 = *(const float4*)(b2 + p*128 + cb + 4);
        const float bv[8] = {bv0.x,bv0.y,bv0.z,bv0.w,bv1.x,bv1.y,bv1.z,bv1.w};
        #pragma unroll
        for (int ee = 0; ee < 8; ++ee)
            #pragma unroll
            for (int cc = 0; cc < 8; ++cc) acc[ee][cc] += bv[cc];
    }
    __syncthreads();
    #pragma unroll
    for (int ee = 0; ee < 8; ++ee) {
        float s = 0.f, q = 0.f;
        #pragma unroll
        for (int cc = 0; cc < 8; ++cc) { s += acc[ee][cc]; q += acc[ee][cc]*acc[ee][cc]; }
        redS[(eb+ee)*16 + (t>>3)] = s;
        redQ[(eb+ee)*16 + (t>>3)] = q;
    }
    __syncthreads();
    if (t < 64) {
        float s = 0.f, q = 0.f;
        #pragma unroll
        for (int k2 = 0; k2 < 16; ++k2) { s += redS[t*16+k2]; q += redQ[t*16+k2]; }
        const float mu  = s * (1.f/128.f);
        const float var = fmaf(-mu, mu, q * (1.f/128.f));
        muA[t] = mu;
        rsA[t] = rsqrtf(var + EPSV);
    }
    __syncthreads();
    {
        const float4 gv0 = *(const float4*)(g2 + p*128 + cb);
        const float4 gv1 = *(const float4*)(g2 + p*128 + cb + 4);
        const float4 hv0 = *(const float4*)(be2 + p*128 + cb);
        const float4 hv1 = *(const float4*)(be2 + p*128 + cb + 4);
        const float gv[8]  = {gv0.x,gv0.y,gv0.z,gv0.w,gv1.x,gv1.y,gv1.z,gv1.w};
        const float bev[8] = {hv0.x,hv0.y,hv0.z,hv0.w,hv1.x,hv1.y,hv1.z,hv1.w};
        #pragma unroll
        for (int ee = 0; ee < 8; ++ee) {
            const float mu = muA[eb+ee], rs = rsA[eb+ee];
            union { float4 f; __half h[8]; } u;
            #pragma unroll
            for (int cc = 0; cc < 8; ++cc)
                u.h[cc] = __float2half(fmaxf(fmaf((acc[ee][cc] - mu) * rs, gv[cc], bev[cc]), 0.f));
            *(float4*)(h2out + (size_t)(e0 + eb + ee) * 128 + cb) = u.f;
        }
    }
}

// ---------------------------------------------------------------- k2a: per-n Em + S-GEMM -> S (fp16)
template<int DI, int DO>
__global__ __launch_bounds__(256) void k2a(
    const float* __restrict__ xsrc,
    const int* __restrict__ nidx,
    const void* __restrict__ nmaskv,
    const float* __restrict__ basis,
    const __half* __restrict__ h2w,
    const float* __restrict__ stats,
    __half* __restrict__ Sp)
{
    constexpr int V  = 2*DI + 1;
    constexpr int U  = 2*DO + 1;
    constexpr int F  = 2*(DI < DO ? DI : DO) + 1;
    constexpr int KF = 16*F;
    constexpr int Q  = 16*U*F;
    constexpr int BP = U*V*F;
    constexpr int XW = 16*V;
    constexpr int CK = 129*KF;
    constexpr int TC = (U == 3) ? 4 : 2;
    constexpr int CT = 128/TC + 1;
    constexpr int K4 = KF/4;

    const int n = blockIdx.x;
    const int t = threadIdx.x;

    __shared__ __align__(16) float Em[JJ*Q];
    __shared__ __align__(16) float Breg[JJ*XW + JJ*BP];
    __shared__ __align__(16) float h2L[JJ*132];
    __shared__ int   idxL[JJ];
    __shared__ float mjf[JJ];

    float* xg   = Breg;
    float* basL = Breg + JJ*XW;

    if (t < JJ) {
        idxL[t] = nidx[n*JJ + t];
        const int useU8 = (stats[30] != 0.f);
        const int mv = useU8 ? (int)((const unsigned char*)nmaskv)[n*JJ + t]
                             : ((const int*)nmaskv)[n*JJ + t];
        mjf[t] = mv ? 1.f : 0.f;
    }
    __syncthreads();

    for (int e = t; e < JJ*XW; e += 256) {
        const int j = e / XW, r = e - j*XW;
        xg[e] = xsrc[idxL[j]*XW + r];
    }
    for (int e = t; e < JJ*BP; e += 256)
        basL[e] = basis[n*JJ*BP + e];
    for (int e = t; e < JJ*128; e += 256) {
        const int j = e >> 7, c = e & 127;
        h2L[j*132 + c] = __half2float(h2w[(size_t)(n*JJ + j)*128 + c]);
    }
    if (t < JJ) {
        h2L[t*132 + 128] = 1.f;
        h2L[t*132 + 129] = 0.f; h2L[t*132 + 130] = 0.f; h2L[t*132 + 131] = 0.f;
    }
    __syncthreads();

    for (int e = t; e < JJ*Q; e += 256) {
        const int j = e / Q, q = e - j*Q;
        const int u = q / KF, k = q - u*KF, i = k / F, f = k - i*F;
        float a = 0.f;
        #pragma unroll
        for (int v = 0; v < V; ++v)
            a = fmaf(basL[j*BP + (u*V + v)*F + f], xg[j*XW + i*V + v], a);
        Em[e] = mjf[j] * a;
    }
    __syncthreads();

    // S[c, u*KF+k] = sum_j h2aug[j,c] * Em[j, u*KF+k] -> Sp[(n*U+u)*CK + c*KF + k] fp16
    for (int task = t; task < CT*K4; task += 256) {
        const int ct = task / K4, k4 = task - ct*K4;
        const int c0 = ct*TC, k0 = k4*4;
        float sacc[TC][U][4];
        #pragma unroll
        for (int a = 0; a < TC; ++a)
            #pragma unroll
            for (int b = 0; b < U; ++b)
                #pragma unroll
                for (int c = 0; c < 4; ++c) sacc[a][b][c] = 0.f;

        for (int j = 0; j < JJ; ++j) {
            float hv[TC];
            if constexpr (TC == 4) {
                const float4 h = *(const float4*)(h2L + j*132 + c0);
                hv[0]=h.x; hv[1]=h.y; hv[2]=h.z; hv[3]=h.w;
            } else {
                const float2 h = *(const float2*)(h2L + j*132 + c0);
                hv[0]=h.x; hv[1]=h.y;
            }
            #pragma unroll
            for (int u = 0; u < U; ++u) {
                const float4 e = *(const float4*)(Em + j*Q + u*KF + k0);
                #pragma unroll
                for (int cc = 0; cc < TC; ++cc) {
                    sacc[cc][u][0] = fmaf(hv[cc], e.x, sacc[cc][u][0]);
                    sacc[cc][u][1] = fmaf(hv[cc], e.y, sacc[cc][u][1]);
                    sacc[cc][u][2] = fmaf(hv[cc], e.z, sacc[cc][u][2]);
                    sacc[cc][u][3] = fmaf(hv[cc], e.w, sacc[cc][u][3]);
                }
            }
        }
        #pragma unroll
        for (int cc = 0; cc < TC; ++cc) {
            if (c0 + cc > 128) continue;
            #pragma unroll
            for (int u = 0; u < U; ++u) {
                union { uint2 uu; __half h[4]; } pk;
                pk.h[0] = __float2half(sacc[cc][u][0]);
                pk.h[1] = __float2half(sacc[cc][u][1]);
                pk.h[2] = __float2half(sacc[cc][u][2]);
                pk.h[3] = __float2half(sacc[cc][u][3]);
                *(uint2*)(Sp + (size_t)(n*U + u)*CK + (c0+cc)*KF + k0) = pk.uu;
            }
        }
    }
}

// ---------------------------------------------------------------- k2b: all pairs, one dispatch
// lane = (row rr, out-channel oo); full dot over CK via v_dot2_f32_f16.
__global__ __launch_bounds__(256) void k2b_all(
    const char* __restrict__ wsbase, const float* __restrict__ dInv,
    float* __restrict__ out)
{
    const int b = blockIdx.x;
    int r0, U, CK, dbase;
    size_t sOff, wOff;
    if (b < 32)       { r0 = b*16;        U=1; CK=2064; sOff=SOFF[0]; wOff=WTOFF[0]; dbase=0; }
    else if (b < 128) { r0 = (b-32)*16;   U=3; CK=2064; sOff=SOFF[1]; wOff=WTOFF[1]; dbase=1; }
    else if (b < 160) { r0 = (b-128)*16;  U=1; CK=2064; sOff=SOFF[2]; wOff=WTOFF[2]; dbase=0; }
    else              { r0 = (b-160)*16;  U=3; CK=6192; sOff=SOFF[3]; wOff=WTOFF[3]; dbase=1; }
    const __half* S  = (const __half*)wsbase + sOff;
    const __half* WT = (const __half*)(wsbase + WT_BYTE) + wOff;

    const int t = threadIdx.x;
    const int lane = t & 63, wv = t >> 6;
    const int rr = lane >> 4, oo = lane & 15;
    const int r = r0 + wv*4 + rr;

    const float4* sp = (const float4*)(S + (size_t)r*CK);    // 8 halfs per float4
    const float4* wp = (const float4*)(WT + (size_t)oo*CK);
    union F4H { float4 f; h2v h[4]; };

    float acc = 0.f;
    const int NI = CK >> 3;
    #pragma unroll 2
    for (int i = 0; i < NI; ++i) {
        F4H sv, wvv;
        sv.f  = sp[i];
        wvv.f = wp[i];
        #pragma unroll
        for (int q = 0; q < 4; ++q)
            acc = __builtin_amdgcn_fdot2(sv.h[q], wvv.h[q], acc, false);
    }
    const int n = r / U, u = r - n*U;
    const int d = dbase ? (1 + u) : 0;
    atomicAdd(out + (size_t)(n*16 + oo)*4 + d, acc * dInv[n]);
}

// ---------------------------------------------------------------- launch
extern "C" void kernel_launch(void* const* d_in, const int* in_sizes, int n_in,
                              void* d_out, int out_size, void* d_ws, size_t ws_size,
                              hipStream_t stream)
{
    const float* x0    = (const float*)d_in[0];
    const float* x1    = (const float*)d_in[1];
    const float* rel   = (const float*)d_in[2];
    const int*   nidx  = (const int*)d_in[3];
    const void*  nmask = d_in[4];
    const float* basis[4] = {(const float*)d_in[5], (const float*)d_in[6],
                             (const float*)d_in[7], (const float*)d_in[8]};
    const float* w1  = (const float*)d_in[9];
    const float* b1  = (const float*)d_in[10];
    const float* g1  = (const float*)d_in[11];
    const float* be1 = (const float*)d_in[12];
    const float* w2  = (const float*)d_in[13];
    const float* b2  = (const float*)d_in[14];
    const float* g2  = (const float*)d_in[15];
    const float* be2 = (const float*)d_in[16];
    const float* w3a[4] = {(const float*)d_in[17], (const float*)d_in[19],
                           (const float*)d_in[21], (const float*)d_in[23]};
    const float* b3a[4] = {(const float*)d_in[18], (const float*)d_in[20],
                           (const float*)d_in[22], (const float*)d_in[24]};
    const float* ks0 = (const float*)d_in[25];
    const float* ks1 = (const float*)d_in[26];
    float* out = (float*)d_out;

    char*   ws    = (char*)d_ws;
    __half* Sall  = (__half*)ws;
    __half* WT2   = (__half*)(ws + WT_BYTE);
    float*  stats = (float*)(ws + ST_BYTE);
    float*  dInv  = (float*)(ws + DI_BYTE);
    __half* h2b   = (__half*)(ws + H2_BYTE);
    const bool merged = ws_size >= 55200000ull;   // constant per session -> graph-safe

    k0_prep<<<904, 256, 0, stream>>>(w1, b1, nmask, x0, x1, ks0, ks1,
                                     w3a[0], b3a[0], w3a[1], b3a[1],
                                     w3a[2], b3a[2], w3a[3], b3a[3],
                                     dInv, out, stats, WT2);

    if (merged) {
        k1_mlp<<<dim3(384, 4), 128, 0, stream>>>(-1, rel, w1, b1, g1, be1, w2, b2, g2, be2,
                                                 stats, h2b, H2_STRIDE);
        k2a<0,0><<<NN, 256, 0, stream>>>(x0, nidx, nmask, basis[0], h2b + 0*H2_STRIDE, stats, Sall + SOFF[0]);
        k2a<0,1><<<NN, 256, 0, stream>>>(x0, nidx, nmask, basis[1], h2b + 1*H2_STRIDE, stats, Sall + SOFF[1]);
        k2a<1,0><<<NN, 256, 0, stream>>>(x1, nidx, nmask, basis[2], h2b + 2*H2_STRIDE, stats, Sall + SOFF[2]);
        k2a<1,1><<<NN, 256, 0, stream>>>(x1, nidx, nmask, basis[3], h2b + 3*H2_STRIDE, stats, Sall + SOFF[3]);
    } else {
        k1_mlp<<<384, 128, 0, stream>>>(0, rel, w1, b1, g1, be1, w2, b2, g2, be2, stats, h2b, 0);
        k2a<0,0><<<NN, 256, 0, stream>>>(x0, nidx, nmask, basis[0], h2b, stats, Sall + SOFF[0]);
        k1_mlp<<<384, 128, 0, stream>>>(1, rel, w1, b1, g1, be1, w2, b2, g2, be2, stats, h2b, 0);
        k2a<0,1><<<NN, 256, 0, stream>>>(x0, nidx, nmask, basis[1], h2b, stats, Sall + SOFF[1]);
        k1_mlp<<<384, 128, 0, stream>>>(2, rel, w1, b1, g1, be1, w2, b2, g2, be2, stats, h2b, 0);
        k2a<1,0><<<NN, 256, 0, stream>>>(x1, nidx, nmask, basis[2], h2b, stats, Sall + SOFF[2]);
        k1_mlp<<<384, 128, 0, stream>>>(3, rel, w1, b1, g1, be1, w2, b2, g2, be2, stats, h2b, 0);
        k2a<1,1><<<NN, 256, 0, stream>>>(x1, nidx, nmask, basis[3], h2b, stats, Sall + SOFF[3]);
    }
    k2b_all<<<256, 256, 0, stream>>>(ws, dInv, out);
}

// Round 5
// 287.378 us; speedup vs baseline: 1.5817x; 1.2668x over previous
//
#include <hip/hip_runtime.h>
#include <hip/hip_fp16.h>

// ConvSE3: B=1, N=512, J=48, M=16, MID=128, pairs (di,do) in {0,1}^2.
//   k0 : LN1 analytic stats, mask probe, dInv, self-interaction init, w3T transpose (fp16)
//   k1 : per-edge radial MLP -> h2 (fp16)   [R5: fp16 h1 LDS -> 8 blocks/CU]
//   k2a: per-n: Em[j,q]=m_j*sum_v basis*xg ; S[c,q]=sum_j h2aug[j,c]*Em[j,q] -> ws (fp16)
//   k2b: all pairs: out[row,o] += dot(S[row,:], w3T[o,:]) * dInv
//        [R5: 1024 blocks, K-split x4 across waves, unroll-4 in-flight loads, LDS reduce]

#define EPSV 1e-5f
constexpr int NN  = 512;
constexpr int JJ  = 48;
constexpr int EE  = NN * JJ;   // 24576 edges

constexpr size_t SOFF[4]  = {0, 1056768, 4227072, 5283840};
constexpr size_t WTOFF[4] = {0, 33024, 66048, 99072};
constexpr size_t WT_BYTE   = 29589504;
constexpr size_t ST_BYTE   = 29985792;
constexpr size_t DI_BYTE   = 29985920;
constexpr size_t H2_BYTE   = 29987968;
constexpr size_t H2_STRIDE = 3145728;      // elems per pair

typedef _Float16 f16_t;
typedef __attribute__((ext_vector_type(2))) _Float16 h2v;

// ---------------------------------------------------------------- k0
__global__ __launch_bounds__(256) void k0_prep(
    const float* __restrict__ w1, const float* __restrict__ b1,
    const void* __restrict__ nmask,
    const float* __restrict__ x0, const float* __restrict__ x1,
    const float* __restrict__ ks0, const float* __restrict__ ks1,
    const float* __restrict__ w3_00, const float* __restrict__ b3_00,
    const float* __restrict__ w3_01, const float* __restrict__ b3_01,
    const float* __restrict__ w3_10, const float* __restrict__ b3_10,
    const float* __restrict__ w3_11, const float* __restrict__ b3_11,
    float* __restrict__ dInv, float* __restrict__ out, float* __restrict__ stats,
    __half* __restrict__ WT2)
{
    const int t = threadIdx.x;
    if (blockIdx.x == 0) {
        const int p = t >> 6, lane = t & 63;
        const float w0 = w1[p*128 + lane],       b0 = b1[p*128 + lane];
        const float w1v = w1[p*128 + 64 + lane], b1v = b1[p*128 + 64 + lane];
        float sw = w0 + w1v, sb = b0 + b1v;
        float sww = w0*w0 + w1v*w1v, swb = w0*b0 + w1v*b1v, sbb = b0*b0 + b1v*b1v;
        for (int off = 32; off > 0; off >>= 1) {
            sw  += __shfl_down(sw, off);  sb  += __shfl_down(sb, off);
            sww += __shfl_down(sww, off); swb += __shfl_down(swb, off);
            sbb += __shfl_down(sbb, off);
        }
        if (lane == 0) {
            const float wbar = sw*(1.f/128.f), bbar = sb*(1.f/128.f);
            stats[p*8+0] = wbar; stats[p*8+1] = bbar;
            stats[p*8+2] = sww*(1.f/128.f) - wbar*wbar;
            stats[p*8+3] = swb*(1.f/128.f) - wbar*bbar;
            stats[p*8+4] = sbb*(1.f/128.f) - bbar*bbar;
        }
        return;
    }
    if (blockIdx.x == 1) {
        __shared__ int flag;
        if (t == 0) flag = 0;
        __syncthreads();
        const int* m32 = (const int*)nmask;
        int bad = 0;
        for (int i = t; i < EE/4; i += 256) if ((unsigned)m32[i] > 1u) bad = 1;
        if (bad) flag = 1;
        __syncthreads();
        const int useU8 = flag;
        if (t == 0) stats[30] = useU8 ? 1.f : 0.f;
        for (int n = t; n < NN; n += 256) {
            float s = 0.f;
            if (useU8) {
                const unsigned char* m8 = (const unsigned char*)nmask;
                for (int j = 0; j < JJ; ++j) s += m8[n*JJ + j] ? 1.f : 0.f;
            } else {
                for (int j = 0; j < JJ; ++j) s += m32[n*JJ + j] ? 1.f : 0.f;
            }
            dInv[n] = 1.f / s;
        }
        return;
    }
    if (blockIdx.x < 130) {
        const int gid = (blockIdx.x - 2) * 256 + t;
        const int d = gid & 3, o = (gid >> 2) & 15, n = gid >> 6;
        float acc = 0.f;
        if (d == 0) {
            #pragma unroll
            for (int i = 0; i < 16; ++i) acc += ks0[o*16+i] * x0[n*16+i];
        } else {
            const int u = d - 1;
            #pragma unroll
            for (int i = 0; i < 16; ++i) acc += ks1[o*16+i] * x1[(n*16+i)*3 + u];
        }
        out[gid] = acc;
        return;
    }
    const int gid = (blockIdx.x - 130) * 256 + t;   // [0, 198144)
    int p, base;
    if      (gid < 33024)  { p = 0; base = 0; }
    else if (gid < 66048)  { p = 1; base = 33024; }
    else if (gid < 99072)  { p = 2; base = 66048; }
    else                   { p = 3; base = 99072; }
    const int KF = (p == 3) ? 48 : 16;
    const int CK = 129*KF;
    const int e = gid - base;
    const int o = e / CK, ck = e - o*CK;
    const int c = ck / KF, k = ck - c*KF;
    const float* w3 = (p==0) ? w3_00 : (p==1) ? w3_01 : (p==2) ? w3_10 : w3_11;
    const float* b3 = (p==0) ? b3_00 : (p==1) ? b3_01 : (p==2) ? b3_10 : b3_11;
    const float v = (c < 128) ? w3[(size_t)c*(16*KF) + o*KF + k] : b3[o*KF + k];
    WT2[base + (size_t)o*CK + ck] = __float2half(v);
}

// ---------------------------------------------------------------- k1: radial MLP
__global__ __launch_bounds__(128, 4) void k1_mlp(
    const int pfix,
    const float* __restrict__ rel,
    const float* __restrict__ w1, const float* __restrict__ b1,
    const float* __restrict__ g1, const float* __restrict__ be1,
    const float* __restrict__ w2, const float* __restrict__ b2,
    const float* __restrict__ g2, const float* __restrict__ be2,
    const float* __restrict__ stats, __half* __restrict__ h2base, const size_t h2stride)
{
    const int p  = (pfix < 0) ? blockIdx.y : pfix;
    __half* h2out = h2base + (size_t)((pfix < 0) ? blockIdx.y : 0) * h2stride;
    const int e0 = blockIdx.x * 64;
    const int t  = threadIdx.x;
    __shared__ __align__(16) _Float16 h1T[128*72];   // [cin][edge] fp16, stride 72 -> 18.4 KB
    __shared__ float dsh[64];
    float* redS = (float*)h1T;            // overlaid after GEMM reads complete
    float* redQ = (float*)h1T + 1024;
    float* muA  = (float*)h1T + 2048;
    float* rsA  = (float*)h1T + 2176;

    if (t < 64) dsh[t] = rel[e0 + t];
    __syncthreads();

    {   // h1 = relu(LN(d*w1+b1)) via analytic LN stats; thread t = cin
        const float w  = w1[p*128 + t], b  = b1[p*128 + t];
        const float g  = g1[p*128 + t], be = be1[p*128 + t];
        const float wbar = stats[p*8+0], bbar = stats[p*8+1];
        const float Cw = stats[p*8+2], Cwb = stats[p*8+3], Cb = stats[p*8+4];
        #pragma unroll 4
        for (int e = 0; e < 64; e += 2) {
            union { _Float16 h[2]; unsigned u; } pk;
            #pragma unroll
            for (int s = 0; s < 2; ++s) {
                const float d   = dsh[e + s];
                const float mu  = fmaf(d, wbar, bbar);
                const float var = fmaf(d*d, Cw, fmaf(2.f*d, Cwb, Cb));
                const float y   = fmaf((fmaf(d, w, b) - mu) * rsqrtf(var + EPSV), g, be);
                pk.h[s] = (_Float16)fmaxf(y, 0.f);
            }
            *(unsigned*)(h1T + t*72 + e) = pk.u;
        }
    }
    __syncthreads();

    const int eb = (t & 7) * 8;
    const int cb = (t >> 3) * 8;
    float acc[8][8];
    #pragma unroll
    for (int a = 0; a < 8; ++a)
        #pragma unroll
        for (int c = 0; c < 8; ++c) acc[a][c] = 0.f;

    const float* __restrict__ w2p = w2 + p*16384;
    for (int k = 0; k < 128; ++k) {
        union { float4 f; _Float16 h[8]; } ua;
        ua.f = *(const float4*)(h1T + k*72 + eb);
        const float4 v0 = *(const float4*)(w2p + k*128 + cb);
        const float4 v1 = *(const float4*)(w2p + k*128 + cb + 4);
        float av[8];
        #pragma unroll
        for (int j = 0; j < 8; ++j) av[j] = (float)ua.h[j];
        const float wv[8] = {v0.x,v0.y,v0.z,v0.w,v1.x,v1.y,v1.z,v1.w};
        #pragma unroll
        for (int ee = 0; ee < 8; ++ee)
            #pragma unroll
            for (int cc = 0; cc < 8; ++cc)
                acc[ee][cc] = fmaf(av[ee], wv[cc], acc[ee][cc]);
    }
    {
        const float4 bv0 = *(const float4*)(b2 + p*128 + cb);
        const float4 bv1 = *(const float4*)(b2 + p*128 + cb + 4);
        const float bv[8] = {bv0.x,bv0.y,bv0.z,bv0.w,bv1.x,bv1.y,bv1.z,bv1.w};
        #pragma unroll
        for (int ee = 0; ee < 8; ++ee)
            #pragma unroll
            for (int cc = 0; cc < 8; ++cc) acc[ee][cc] += bv[cc];
    }
    __syncthreads();   // all h1T reads done before overlaying red arrays
    #pragma unroll
    for (int ee = 0; ee < 8; ++ee) {
        float s = 0.f, q = 0.f;
        #pragma unroll
        for (int cc = 0; cc < 8; ++cc) { s += acc[ee][cc]; q += acc[ee][cc]*acc[ee][cc]; }
        redS[(eb+ee)*16 + (t>>3)] = s;
        redQ[(eb+ee)*16 + (t>>3)] = q;
    }
    __syncthreads();
    if (t < 64) {
        float s = 0.f, q = 0.f;
        #pragma unroll
        for (int k2 = 0; k2 < 16; ++k2) { s += redS[t*16+k2]; q += redQ[t*16+k2]; }
        const float mu  = s * (1.f/128.f);
        const float var = fmaf(-mu, mu, q * (1.f/128.f));
        muA[t] = mu;
        rsA[t] = rsqrtf(var + EPSV);
    }
    __syncthreads();
    {
        const float4 gv0 = *(const float4*)(g2 + p*128 + cb);
        const float4 gv1 = *(const float4*)(g2 + p*128 + cb + 4);
        const float4 hv0 = *(const float4*)(be2 + p*128 + cb);
        const float4 hv1 = *(const float4*)(be2 + p*128 + cb + 4);
        const float gv[8]  = {gv0.x,gv0.y,gv0.z,gv0.w,gv1.x,gv1.y,gv1.z,gv1.w};
        const float bev[8] = {hv0.x,hv0.y,hv0.z,hv0.w,hv1.x,hv1.y,hv1.z,hv1.w};
        #pragma unroll
        for (int ee = 0; ee < 8; ++ee) {
            const float mu = muA[eb+ee], rs = rsA[eb+ee];
            union { float4 f; __half h[8]; } u;
            #pragma unroll
            for (int cc = 0; cc < 8; ++cc)
                u.h[cc] = __float2half(fmaxf(fmaf((acc[ee][cc] - mu) * rs, gv[cc], bev[cc]), 0.f));
            *(float4*)(h2out + (size_t)(e0 + eb + ee) * 128 + cb) = u.f;
        }
    }
}

// ---------------------------------------------------------------- k2a: per-n Em + S-GEMM -> S (fp16)
template<int DI, int DO>
__global__ __launch_bounds__(256) void k2a(
    const float* __restrict__ xsrc,
    const int* __restrict__ nidx,
    const void* __restrict__ nmaskv,
    const float* __restrict__ basis,
    const __half* __restrict__ h2w,
    const float* __restrict__ stats,
    __half* __restrict__ Sp)
{
    constexpr int V  = 2*DI + 1;
    constexpr int U  = 2*DO + 1;
    constexpr int F  = 2*(DI < DO ? DI : DO) + 1;
    constexpr int KF = 16*F;
    constexpr int Q  = 16*U*F;
    constexpr int BP = U*V*F;
    constexpr int XW = 16*V;
    constexpr int CK = 129*KF;
    constexpr int TC = (U == 3) ? 4 : 2;
    constexpr int CT = 128/TC + 1;
    constexpr int K4 = KF/4;

    const int n = blockIdx.x;
    const int t = threadIdx.x;

    __shared__ __align__(16) float Em[JJ*Q];
    __shared__ __align__(16) float Breg[JJ*XW + JJ*BP];
    __shared__ __align__(16) float h2L[JJ*132];
    __shared__ int   idxL[JJ];
    __shared__ float mjf[JJ];

    float* xg   = Breg;
    float* basL = Breg + JJ*XW;

    if (t < JJ) {
        idxL[t] = nidx[n*JJ + t];
        const int useU8 = (stats[30] != 0.f);
        const int mv = useU8 ? (int)((const unsigned char*)nmaskv)[n*JJ + t]
                             : ((const int*)nmaskv)[n*JJ + t];
        mjf[t] = mv ? 1.f : 0.f;
    }
    __syncthreads();

    for (int e = t; e < JJ*XW; e += 256) {
        const int j = e / XW, r = e - j*XW;
        xg[e] = xsrc[idxL[j]*XW + r];
    }
    for (int e = t; e < JJ*BP; e += 256)
        basL[e] = basis[n*JJ*BP + e];
    for (int e = t; e < JJ*128; e += 256) {
        const int j = e >> 7, c = e & 127;
        h2L[j*132 + c] = __half2float(h2w[(size_t)(n*JJ + j)*128 + c]);
    }
    if (t < JJ) {
        h2L[t*132 + 128] = 1.f;
        h2L[t*132 + 129] = 0.f; h2L[t*132 + 130] = 0.f; h2L[t*132 + 131] = 0.f;
    }
    __syncthreads();

    for (int e = t; e < JJ*Q; e += 256) {
        const int j = e / Q, q = e - j*Q;
        const int u = q / KF, k = q - u*KF, i = k / F, f = k - i*F;
        float a = 0.f;
        #pragma unroll
        for (int v = 0; v < V; ++v)
            a = fmaf(basL[j*BP + (u*V + v)*F + f], xg[j*XW + i*V + v], a);
        Em[e] = mjf[j] * a;
    }
    __syncthreads();

    for (int task = t; task < CT*K4; task += 256) {
        const int ct = task / K4, k4 = task - ct*K4;
        const int c0 = ct*TC, k0 = k4*4;
        float sacc[TC][U][4];
        #pragma unroll
        for (int a = 0; a < TC; ++a)
            #pragma unroll
            for (int b = 0; b < U; ++b)
                #pragma unroll
                for (int c = 0; c < 4; ++c) sacc[a][b][c] = 0.f;

        for (int j = 0; j < JJ; ++j) {
            float hv[TC];
            if constexpr (TC == 4) {
                const float4 h = *(const float4*)(h2L + j*132 + c0);
                hv[0]=h.x; hv[1]=h.y; hv[2]=h.z; hv[3]=h.w;
            } else {
                const float2 h = *(const float2*)(h2L + j*132 + c0);
                hv[0]=h.x; hv[1]=h.y;
            }
            #pragma unroll
            for (int u = 0; u < U; ++u) {
                const float4 e = *(const float4*)(Em + j*Q + u*KF + k0);
                #pragma unroll
                for (int cc = 0; cc < TC; ++cc) {
                    sacc[cc][u][0] = fmaf(hv[cc], e.x, sacc[cc][u][0]);
                    sacc[cc][u][1] = fmaf(hv[cc], e.y, sacc[cc][u][1]);
                    sacc[cc][u][2] = fmaf(hv[cc], e.z, sacc[cc][u][2]);
                    sacc[cc][u][3] = fmaf(hv[cc], e.w, sacc[cc][u][3]);
                }
            }
        }
        #pragma unroll
        for (int cc = 0; cc < TC; ++cc) {
            if (c0 + cc > 128) continue;
            #pragma unroll
            for (int u = 0; u < U; ++u) {
                union { uint2 uu; __half h[4]; } pk;
                pk.h[0] = __float2half(sacc[cc][u][0]);
                pk.h[1] = __float2half(sacc[cc][u][1]);
                pk.h[2] = __float2half(sacc[cc][u][2]);
                pk.h[3] = __float2half(sacc[cc][u][3]);
                *(uint2*)(Sp + (size_t)(n*U + u)*CK + (c0+cc)*KF + k0) = pk.uu;
            }
        }
    }
}

// ---------------------------------------------------------------- k2b: all pairs, one dispatch
// 1024 blocks: 4 rows x 16 o each; waves = K-split x4 (wave-uniform), LDS reduce, 1 atomic/(row,o).
__global__ __launch_bounds__(256) void k2b_all(
    const char* __restrict__ wsbase, const float* __restrict__ dInv,
    float* __restrict__ out)
{
    const int b = blockIdx.x;
    int lr0, U, CK, dbase;
    size_t sOff, wOff;
    if (b < 128)      { lr0 = b*4;        U=1; CK=2064; sOff=SOFF[0]; wOff=WTOFF[0]; dbase=0; }
    else if (b < 512) { lr0 = (b-128)*4;  U=3; CK=2064; sOff=SOFF[1]; wOff=WTOFF[1]; dbase=1; }
    else if (b < 640) { lr0 = (b-512)*4;  U=1; CK=2064; sOff=SOFF[2]; wOff=WTOFF[2]; dbase=0; }
    else              { lr0 = (b-640)*4;  U=3; CK=6192; sOff=SOFF[3]; wOff=WTOFF[3]; dbase=1; }
    const __half* S  = (const __half*)wsbase + sOff;
    const __half* WT = (const __half*)(wsbase + WT_BYTE) + wOff;

    const int t = threadIdx.x;
    const int ks = t >> 6;            // wave-uniform K-split index
    const int rr = (t >> 4) & 3, oo = t & 15;
    const int lr = lr0 + rr;

    const float4* sp = (const float4*)(S + (size_t)lr*CK);
    const float4* wp = (const float4*)(WT + (size_t)oo*CK);
    union F4H { float4 f; h2v h[4]; };

    const int NI4 = CK >> 3;
    float acc = 0.f;
    #pragma unroll 4
    for (int i = ks; i < NI4; i += 4) {
        F4H sv, wvv;
        sv.f  = sp[i];
        wvv.f = wp[i];
        #pragma unroll
        for (int q = 0; q < 4; ++q)
            acc = __builtin_amdgcn_fdot2(sv.h[q], wvv.h[q], acc, false);
    }

    __shared__ float red[4][64];
    red[ks][rr*16 + oo] = acc;
    __syncthreads();
    if (t < 64) {
        const int rr2 = t >> 4, oo2 = t & 15;
        const int lr2 = lr0 + rr2;
        const int n = lr2 / U, u = lr2 - n*U;
        const float s = red[0][t] + red[1][t] + red[2][t] + red[3][t];
        atomicAdd(out + (size_t)(n*16 + oo2)*4 + (dbase ? 1 + u : 0), s * dInv[n]);
    }
}

// ---------------------------------------------------------------- launch
extern "C" void kernel_launch(void* const* d_in, const int* in_sizes, int n_in,
                              void* d_out, int out_size, void* d_ws, size_t ws_size,
                              hipStream_t stream)
{
    const float* x0    = (const float*)d_in[0];
    const float* x1    = (const float*)d_in[1];
    const float* rel   = (const float*)d_in[2];
    const int*   nidx  = (const int*)d_in[3];
    const void*  nmask = d_in[4];
    const float* basis[4] = {(const float*)d_in[5], (const float*)d_in[6],
                             (const float*)d_in[7], (const float*)d_in[8]};
    const float* w1  = (const float*)d_in[9];
    const float* b1  = (const float*)d_in[10];
    const float* g1  = (const float*)d_in[11];
    const float* be1 = (const float*)d_in[12];
    const float* w2  = (const float*)d_in[13];
    const float* b2  = (const float*)d_in[14];
    const float* g2  = (const float*)d_in[15];
    const float* be2 = (const float*)d_in[16];
    const float* w3a[4] = {(const float*)d_in[17], (const float*)d_in[19],
                           (const float*)d_in[21], (const float*)d_in[23]};
    const float* b3a[4] = {(const float*)d_in[18], (const float*)d_in[20],
                           (const float*)d_in[22], (const float*)d_in[24]};
    const float* ks0 = (const float*)d_in[25];
    const float* ks1 = (const float*)d_in[26];
    float* out = (float*)d_out;

    char*   ws    = (char*)d_ws;
    __half* Sall  = (__half*)ws;
    __half* WT2   = (__half*)(ws + WT_BYTE);
    float*  stats = (float*)(ws + ST_BYTE);
    float*  dInv  = (float*)(ws + DI_BYTE);
    __half* h2b   = (__half*)(ws + H2_BYTE);
    const bool merged = ws_size >= 55200000ull;   // constant per session -> graph-safe

    k0_prep<<<904, 256, 0, stream>>>(w1, b1, nmask, x0, x1, ks0, ks1,
                                     w3a[0], b3a[0], w3a[1], b3a[1],
                                     w3a[2], b3a[2], w3a[3], b3a[3],
                                     dInv, out, stats, WT2);

    if (merged) {
        k1_mlp<<<dim3(384, 4), 128, 0, stream>>>(-1, rel, w1, b1, g1, be1, w2, b2, g2, be2,
                                                 stats, h2b, H2_STRIDE);
        k2a<0,0><<<NN, 256, 0, stream>>>(x0, nidx, nmask, basis[0], h2b + 0*H2_STRIDE, stats, Sall + SOFF[0]);
        k2a<0,1><<<NN, 256, 0, stream>>>(x0, nidx, nmask, basis[1], h2b + 1*H2_STRIDE, stats, Sall + SOFF[1]);
        k2a<1,0><<<NN, 256, 0, stream>>>(x1, nidx, nmask, basis[2], h2b + 2*H2_STRIDE, stats, Sall + SOFF[2]);
        k2a<1,1><<<NN, 256, 0, stream>>>(x1, nidx, nmask, basis[3], h2b + 3*H2_STRIDE, stats, Sall + SOFF[3]);
    } else {
        k1_mlp<<<384, 128, 0, stream>>>(0, rel, w1, b1, g1, be1, w2, b2, g2, be2, stats, h2b, 0);
        k2a<0,0><<<NN, 256, 0, stream>>>(x0, nidx, nmask, basis[0], h2b, stats, Sall + SOFF[0]);
        k1_mlp<<<384, 128, 0, stream>>>(1, rel, w1, b1, g1, be1, w2, b2, g2, be2, stats, h2b, 0);
        k2a<0,1><<<NN, 256, 0, stream>>>(x0, nidx, nmask, basis[1], h2b, stats, Sall + SOFF[1]);
        k1_mlp<<<384, 128, 0, stream>>>(2, rel, w1, b1, g1, be1, w2, b2, g2, be2, stats, h2b, 0);
        k2a<1,0><<<NN, 256, 0, stream>>>(x1, nidx, nmask, basis[2], h2b, stats, Sall + SOFF[2]);
        k1_mlp<<<384, 128, 0, stream>>>(3, rel, w1, b1, g1, be1, w2, b2, g2, be2, stats, h2b, 0);
        k2a<1,1><<<NN, 256, 0, stream>>>(x1, nidx, nmask, basis[3], h2b, stats, Sall + SOFF[3]);
    }
    k2b_all<<<1024, 256, 0, stream>>>(ws, dInv, out);
}

// Round 6
// 222.174 us; speedup vs baseline: 2.0459x; 1.2935x over previous
//
#include <hip/hip_runtime.h>
#include <hip/hip_fp16.h>

// ConvSE3: B=1, N=512, J=48, M=16, MID=128, pairs (di,do) in {0,1}^2.
//   k0 : LN1 stats, mask probe, dInv, self-init, w3T->WT fp16 (padded), w2T fp16
//   k1 : radial MLP via MFMA 16x16x32 f16 (h1,w2 fp16 LDS; LN2 in-register) -> h2 fp16
//   k2a: per-n Em + S-GEMM -> S fp16 (rows padded to CKP = CK+16, zero pad)
//   k2b: out[row,o] += S[row,:]*WT[o,:] via MFMA (m-tile/block, K-split x4 waves)
// R6: MFMA replaces scalar GEMMs in k1 (was VALU-bound 67us) and k2b (was
// vmem-issue-bound 63us from 16x redundant S reads).

#define EPSV 1e-5f
constexpr int NN  = 512;
constexpr int JJ  = 48;
constexpr int EE  = NN * JJ;   // 24576 edges

// ---- workspace layout (bytes) -------------------------------------------
// [0)        WT fp16 [16][CKP] per pair (CKP=2080,2080,2080,6208), 398336 B
// [398336)   stats 32 f32 ; [398464) dInv 512 f32
// [401408)   S fp16 (padded rows), 29.72 MB ; w2h fp16 aliased at S start
// h2 fp16 windows (6.29 MB each) lifetime-overlapped with S (see offsets)
constexpr size_t WTOFFS[4] = {0, 33280, 66560, 99840};        // halfs
constexpr size_t ST_BYTE = 398336;
constexpr size_t DI_BYTE = 398464;
constexpr size_t S_BYTE  = 401408;
constexpr size_t SOFFS[4] = {0, 1064960, 4259840, 5324800};   // halfs rel S_BYTE
constexpr size_t W2H_BYTE = S_BYTE;                           // alias: dead before k2a(0)
constexpr size_t H2OFF[4] = {23633920, 17342464, 11051008, 30121984};  // bytes

typedef _Float16 f16_t;
typedef __attribute__((ext_vector_type(8))) _Float16 v8h;
typedef __attribute__((ext_vector_type(4))) float v4f;

// ---------------------------------------------------------------- k0
__global__ __launch_bounds__(256) void k0_prep(
    const float* __restrict__ w1, const float* __restrict__ b1,
    const void* __restrict__ nmask,
    const float* __restrict__ x0, const float* __restrict__ x1,
    const float* __restrict__ ks0, const float* __restrict__ ks1,
    const float* __restrict__ w2,
    const float* __restrict__ w3_00, const float* __restrict__ b3_00,
    const float* __restrict__ w3_01, const float* __restrict__ b3_01,
    const float* __restrict__ w3_10, const float* __restrict__ b3_10,
    const float* __restrict__ w3_11, const float* __restrict__ b3_11,
    float* __restrict__ dInv, float* __restrict__ out, float* __restrict__ stats,
    _Float16* __restrict__ WT, _Float16* __restrict__ w2h)
{
    const int t = threadIdx.x;
    if (blockIdx.x == 0) {
        const int p = t >> 6, lane = t & 63;
        const float w0 = w1[p*128 + lane],       b0 = b1[p*128 + lane];
        const float w1v = w1[p*128 + 64 + lane], b1v = b1[p*128 + 64 + lane];
        float sw = w0 + w1v, sb = b0 + b1v;
        float sww = w0*w0 + w1v*w1v, swb = w0*b0 + w1v*b1v, sbb = b0*b0 + b1v*b1v;
        for (int off = 32; off > 0; off >>= 1) {
            sw  += __shfl_down(sw, off);  sb  += __shfl_down(sb, off);
            sww += __shfl_down(sww, off); swb += __shfl_down(swb, off);
            sbb += __shfl_down(sbb, off);
        }
        if (lane == 0) {
            const float wbar = sw*(1.f/128.f), bbar = sb*(1.f/128.f);
            stats[p*8+0] = wbar; stats[p*8+1] = bbar;
            stats[p*8+2] = sww*(1.f/128.f) - wbar*wbar;
            stats[p*8+3] = swb*(1.f/128.f) - wbar*bbar;
            stats[p*8+4] = sbb*(1.f/128.f) - bbar*bbar;
        }
        return;
    }
    if (blockIdx.x == 1) {
        __shared__ int flag;
        if (t == 0) flag = 0;
        __syncthreads();
        const int* m32 = (const int*)nmask;
        int bad = 0;
        for (int i = t; i < EE/4; i += 256) if ((unsigned)m32[i] > 1u) bad = 1;
        if (bad) flag = 1;
        __syncthreads();
        const int useU8 = flag;
        if (t == 0) stats[30] = useU8 ? 1.f : 0.f;
        for (int n = t; n < NN; n += 256) {
            float s = 0.f;
            if (useU8) {
                const unsigned char* m8 = (const unsigned char*)nmask;
                for (int j = 0; j < JJ; ++j) s += m8[n*JJ + j] ? 1.f : 0.f;
            } else {
                for (int j = 0; j < JJ; ++j) s += m32[n*JJ + j] ? 1.f : 0.f;
            }
            dInv[n] = 1.f / s;
        }
        return;
    }
    if (blockIdx.x < 130) {              // self-interaction init
        const int gid = (blockIdx.x - 2) * 256 + t;
        const int d = gid & 3, o = (gid >> 2) & 15, n = gid >> 6;
        float acc = 0.f;
        if (d == 0) {
            #pragma unroll
            for (int i = 0; i < 16; ++i) acc += ks0[o*16+i] * x0[n*16+i];
        } else {
            const int u = d - 1;
            #pragma unroll
            for (int i = 0; i < 16; ++i) acc += ks1[o*16+i] * x1[(n*16+i)*3 + u];
        }
        out[gid] = acc;
        return;
    }
    if (blockIdx.x < 908) {              // WT: [o][CKP] fp16, zero-padded tail
        const int gid = (blockIdx.x - 130) * 256 + t;   // [0, 199168)
        if (gid >= 199168) return;
        int p, base;
        if      (gid < 33280)  { p = 0; base = 0; }
        else if (gid < 66560)  { p = 1; base = 33280; }
        else if (gid < 99840)  { p = 2; base = 66560; }
        else                   { p = 3; base = 99840; }
        const int KF = (p == 3) ? 48 : 16;
        const int CK = 129*KF, CKP = CK + 16;
        const int e = gid - base;
        const int o = e / CKP, ck = e - o*CKP;
        float v = 0.f;
        if (ck < CK) {
            const int c = ck / KF, k = ck - c*KF;
            const float* w3 = (p==0) ? w3_00 : (p==1) ? w3_01 : (p==2) ? w3_10 : w3_11;
            const float* b3 = (p==0) ? b3_00 : (p==1) ? b3_01 : (p==2) ? b3_10 : b3_11;
            v = (c < 128) ? w3[(size_t)c*(16*KF) + o*KF + k] : b3[o*KF + k];
        }
        WT[base + (size_t)o*CKP + ck] = (_Float16)v;
        return;
    }
    // w2 transpose -> fp16: w2h[p][c][k] = w2[p][k][c]
    const int gid = (blockIdx.x - 908) * 256 + t;       // [0, 65536)
    const int p = gid >> 14, rem = gid & 16383;
    const int c = rem >> 7, k = rem & 127;
    w2h[gid] = (_Float16)w2[p*16384 + k*128 + c];
}

// ---------------------------------------------------------------- k1: radial MLP (MFMA)
// grid (384, 4): 64 edges/block, pair = blockIdx.y, 256 threads (4 waves x 16 rows)
__global__ __launch_bounds__(256, 2) void k1_mfma(
    const float* __restrict__ rel,
    const float* __restrict__ w1, const float* __restrict__ b1,
    const float* __restrict__ g1, const float* __restrict__ be1,
    const float* __restrict__ b2, const float* __restrict__ g2,
    const float* __restrict__ be2,
    const float* __restrict__ stats, const char* __restrict__ ws)
{
    const int p  = blockIdx.y;
    const int e0 = blockIdx.x * 64;
    const int t  = threadIdx.x;
    const _Float16* __restrict__ w2h = (const _Float16*)(ws + W2H_BYTE) + (size_t)p*16384;
    _Float16* __restrict__ h2out = (_Float16*)(ws + H2OFF[p]);

    __shared__ __align__(16) _Float16 h1L[64*136];    // [edge][cin], stride 136
    __shared__ __align__(16) _Float16 w2L[128*136];   // [cout][cin] (= w2^T), stride 136
    __shared__ float dsh[64];
    __shared__ float pb[384];                         // b2 | g2 | be2

    if (t < 64) dsh[t] = rel[e0 + t];
    if (t < 128) {
        pb[t]       = b2[p*128 + t];
        pb[128 + t] = g2[p*128 + t];
        pb[256 + t] = be2[p*128 + t];
    }
    for (int i = t; i < 2048; i += 256) {             // w2L copy: 2048 x b128
        const int c = i >> 4, off = (i & 15) * 8;
        *(float4*)(w2L + c*136 + off) = *(const float4*)(w2h + c*128 + off);
    }
    __syncthreads();

    {   // phase 1: h1 = relu(LN1(d*w1+b1)) analytic; thread = cin, 32 edges
        const int cin = t & 127, eh = t >> 7;
        const float w  = w1[p*128 + cin], b  = b1[p*128 + cin];
        const float g  = g1[p*128 + cin], be = be1[p*128 + cin];
        const float wbar = stats[p*8+0], bbar = stats[p*8+1];
        const float Cw = stats[p*8+2], Cwb = stats[p*8+3], Cb = stats[p*8+4];
        for (int e = eh*32; e < eh*32 + 32; ++e) {
            const float d   = dsh[e];
            const float mu  = fmaf(d, wbar, bbar);
            const float var = fmaf(d*d, Cw, fmaf(2.f*d, Cwb, Cb));
            const float y   = fmaf((fmaf(d, w, b) - mu) * rsqrtf(var + EPSV), g, be);
            h1L[e*136 + cin] = (_Float16)fmaxf(y, 0.f);
        }
    }
    __syncthreads();

    // phase 2: h2pre[64x128] = h1 @ w2 via MFMA; wave w owns rows m0..m0+15
    const int l = t & 63, wv = t >> 6;
    const int q = l >> 4, c16 = l & 15;
    const int m0 = wv * 16;
    v4f acc[8];
    #pragma unroll
    for (int nt = 0; nt < 8; ++nt) { acc[nt][0]=0.f; acc[nt][1]=0.f; acc[nt][2]=0.f; acc[nt][3]=0.f; }

    #pragma unroll
    for (int ks = 0; ks < 4; ++ks) {
        const int k0 = ks*32 + q*8;
        const v8h a = *(const v8h*)(h1L + (m0 + c16)*136 + k0);
        #pragma unroll
        for (int nt = 0; nt < 8; ++nt) {
            const v8h bf = *(const v8h*)(w2L + (nt*16 + c16)*136 + k0);
            acc[nt] = __builtin_amdgcn_mfma_f32_16x16x32_f16(a, bf, acc[nt], 0, 0, 0);
        }
    }

    // phase 3: +b2, LN2 (shuffle reduce over cout), scale, relu -> h1L (fp16)
    float bl[8], gl[8], bel[8];
    #pragma unroll
    for (int nt = 0; nt < 8; ++nt) {
        bl[nt]  = pb[nt*16 + c16];
        gl[nt]  = pb[128 + nt*16 + c16];
        bel[nt] = pb[256 + nt*16 + c16];
    }
    #pragma unroll
    for (int nt = 0; nt < 8; ++nt)
        #pragma unroll
        for (int r = 0; r < 4; ++r) acc[nt][r] += bl[nt];

    #pragma unroll
    for (int r = 0; r < 4; ++r) {
        float s = 0.f, qq = 0.f;
        #pragma unroll
        for (int nt = 0; nt < 8; ++nt) { const float v = acc[nt][r]; s += v; qq += v*v; }
        #pragma unroll
        for (int m = 1; m < 16; m <<= 1) { s += __shfl_xor(s, m); qq += __shfl_xor(qq, m); }
        const float mu = s * (1.f/128.f);
        const float rs = rsqrtf(qq*(1.f/128.f) - mu*mu + EPSV);
        const int e = m0 + q*4 + r;
        #pragma unroll
        for (int nt = 0; nt < 8; ++nt) {
            const float v = fmaxf(fmaf((acc[nt][r] - mu)*rs, gl[nt], bel[nt]), 0.f);
            h1L[e*136 + nt*16 + c16] = (_Float16)v;   // own rows only: no barrier needed
        }
    }
    __syncthreads();

    for (int i = t; i < 1024; i += 256) {             // coalesced h2 write
        const int e = i >> 4, off = (i & 15) * 8;
        *(float4*)(h2out + (size_t)(e0 + e)*128 + off) = *(const float4*)(h1L + e*136 + off);
    }
}

// ---------------------------------------------------------------- k2a: per-n Em + S-GEMM -> S fp16 (padded)
template<int DI, int DO>
__global__ __launch_bounds__(256) void k2a(
    const float* __restrict__ xsrc,
    const int* __restrict__ nidx,
    const void* __restrict__ nmaskv,
    const float* __restrict__ basis,
    const __half* __restrict__ h2w,
    const float* __restrict__ stats,
    __half* __restrict__ Sp)
{
    constexpr int V  = 2*DI + 1;
    constexpr int U  = 2*DO + 1;
    constexpr int F  = 2*(DI < DO ? DI : DO) + 1;
    constexpr int KF = 16*F;
    constexpr int Q  = 16*U*F;
    constexpr int BP = U*V*F;
    constexpr int XW = 16*V;
    constexpr int CK = 129*KF;
    constexpr int CKP = CK + 16;
    constexpr int TC = (U == 3) ? 4 : 2;
    constexpr int CT = 128/TC + 1;
    constexpr int K4 = KF/4;

    const int n = blockIdx.x;
    const int t = threadIdx.x;

    __shared__ __align__(16) float Em[JJ*Q];
    __shared__ __align__(16) float Breg[JJ*XW + JJ*BP];
    __shared__ __align__(16) float h2L[JJ*132];
    __shared__ int   idxL[JJ];
    __shared__ float mjf[JJ];

    float* xg   = Breg;
    float* basL = Breg + JJ*XW;

    if (t < JJ) {
        idxL[t] = nidx[n*JJ + t];
        const int useU8 = (stats[30] != 0.f);
        const int mv = useU8 ? (int)((const unsigned char*)nmaskv)[n*JJ + t]
                             : ((const int*)nmaskv)[n*JJ + t];
        mjf[t] = mv ? 1.f : 0.f;
    }
    if (t < U*16) {   // zero the K-pad of this n's rows
        const int u = t >> 4, i2 = t & 15;
        Sp[(size_t)(n*U + u)*CKP + CK + i2] = __float2half(0.f);
    }
    __syncthreads();

    for (int e = t; e < JJ*XW; e += 256) {
        const int j = e / XW, r = e - j*XW;
        xg[e] = xsrc[idxL[j]*XW + r];
    }
    for (int e = t; e < JJ*BP; e += 256)
        basL[e] = basis[n*JJ*BP + e];
    for (int e = t; e < JJ*128; e += 256) {
        const int j = e >> 7, c = e & 127;
        h2L[j*132 + c] = __half2float(h2w[(size_t)(n*JJ + j)*128 + c]);
    }
    if (t < JJ) {
        h2L[t*132 + 128] = 1.f;
        h2L[t*132 + 129] = 0.f; h2L[t*132 + 130] = 0.f; h2L[t*132 + 131] = 0.f;
    }
    __syncthreads();

    for (int e = t; e < JJ*Q; e += 256) {
        const int j = e / Q, q = e - j*Q;
        const int u = q / KF, k = q - u*KF, i = k / F, f = k - i*F;
        float a = 0.f;
        #pragma unroll
        for (int v = 0; v < V; ++v)
            a = fmaf(basL[j*BP + (u*V + v)*F + f], xg[j*XW + i*V + v], a);
        Em[e] = mjf[j] * a;
    }
    __syncthreads();

    for (int task = t; task < CT*K4; task += 256) {
        const int ct = task / K4, k4 = task - ct*K4;
        const int c0 = ct*TC, k0 = k4*4;
        float sacc[TC][U][4];
        #pragma unroll
        for (int a = 0; a < TC; ++a)
            #pragma unroll
            for (int b = 0; b < U; ++b)
                #pragma unroll
                for (int c = 0; c < 4; ++c) sacc[a][b][c] = 0.f;

        for (int j = 0; j < JJ; ++j) {
            float hv[TC];
            if constexpr (TC == 4) {
                const float4 h = *(const float4*)(h2L + j*132 + c0);
                hv[0]=h.x; hv[1]=h.y; hv[2]=h.z; hv[3]=h.w;
            } else {
                const float2 h = *(const float2*)(h2L + j*132 + c0);
                hv[0]=h.x; hv[1]=h.y;
            }
            #pragma unroll
            for (int u = 0; u < U; ++u) {
                const float4 e = *(const float4*)(Em + j*Q + u*KF + k0);
                #pragma unroll
                for (int cc = 0; cc < TC; ++cc) {
                    sacc[cc][u][0] = fmaf(hv[cc], e.x, sacc[cc][u][0]);
                    sacc[cc][u][1] = fmaf(hv[cc], e.y, sacc[cc][u][1]);
                    sacc[cc][u][2] = fmaf(hv[cc], e.z, sacc[cc][u][2]);
                    sacc[cc][u][3] = fmaf(hv[cc], e.w, sacc[cc][u][3]);
                }
            }
        }
        #pragma unroll
        for (int cc = 0; cc < TC; ++cc) {
            if (c0 + cc > 128) continue;
            #pragma unroll
            for (int u = 0; u < U; ++u) {
                union { uint2 uu; __half h[4]; } pk;
                pk.h[0] = __float2half(sacc[cc][u][0]);
                pk.h[1] = __float2half(sacc[cc][u][1]);
                pk.h[2] = __float2half(sacc[cc][u][2]);
                pk.h[3] = __float2half(sacc[cc][u][3]);
                *(uint2*)(Sp + (size_t)(n*U + u)*CKP + (c0+cc)*KF + k0) = pk.uu;
            }
        }
    }
}

// ---------------------------------------------------------------- k2b: MFMA GEMM out += S * WT^T
// 256 blocks = 16-row m-tiles across all pairs; 4 waves = K-split; LDS reduce; atomicAdd.
__global__ __launch_bounds__(256) void k2b_mfma(
    const char* __restrict__ wsbase, const float* __restrict__ dInv,
    float* __restrict__ out)
{
    const int b = blockIdx.x;
    int pair, mt;
    if (b < 32)       { pair = 0; mt = b; }
    else if (b < 128) { pair = 1; mt = b - 32; }
    else if (b < 160) { pair = 2; mt = b - 128; }
    else              { pair = 3; mt = b - 160; }
    const int U     = (pair == 1 || pair == 3) ? 3 : 1;
    const int dbase = (U == 3) ? 1 : 0;
    const int CKP   = (pair == 3) ? 6208 : 2080;
    const int NK    = CKP >> 5;                    // 194 or 65
    const _Float16* S  = (const _Float16*)(wsbase + S_BYTE) + SOFFS[pair];
    const _Float16* WT = (const _Float16*)wsbase + WTOFFS[pair];

    const int t = threadIdx.x;
    const int wv = t >> 6, l = t & 63;
    const int q = l >> 4, c16 = l & 15;
    const int KC = (NK + 3) >> 2;
    const int k_lo = wv * KC;
    const int k_hi = (k_lo + KC < NK) ? (k_lo + KC) : NK;

    const int row0 = mt * 16;
    const _Float16* sp = S  + (size_t)(row0 + c16) * CKP + q*8;
    const _Float16* wp = WT + (size_t)c16 * CKP + q*8;

    v4f acc; acc[0]=0.f; acc[1]=0.f; acc[2]=0.f; acc[3]=0.f;
    #pragma unroll 4
    for (int ks = k_lo; ks < k_hi; ++ks) {
        const v8h a  = *(const v8h*)(sp + ks*32);
        const v8h bf = *(const v8h*)(wp + ks*32);
        acc = __builtin_amdgcn_mfma_f32_16x16x32_f16(a, bf, acc, 0, 0, 0);
    }

    __shared__ float red[4][16][16];
    #pragma unroll
    for (int r = 0; r < 4; ++r) red[wv][q*4 + r][c16] = acc[r];
    __syncthreads();

    {
        const int r16 = t >> 4, o = t & 15;
        const float v = red[0][r16][o] + red[1][r16][o] + red[2][r16][o] + red[3][r16][o];
        const int row = row0 + r16;
        int n, u;
        if (U == 1) { n = row; u = 0; }
        else        { n = row / 3; u = row - n*3; }
        atomicAdd(out + (size_t)(n*16 + o)*4 + (dbase ? 1 + u : 0), v * dInv[n]);
    }
}

// ---------------------------------------------------------------- launch
extern "C" void kernel_launch(void* const* d_in, const int* in_sizes, int n_in,
                              void* d_out, int out_size, void* d_ws, size_t ws_size,
                              hipStream_t stream)
{
    const float* x0    = (const float*)d_in[0];
    const float* x1    = (const float*)d_in[1];
    const float* rel   = (const float*)d_in[2];
    const int*   nidx  = (const int*)d_in[3];
    const void*  nmask = d_in[4];
    const float* basis[4] = {(const float*)d_in[5], (const float*)d_in[6],
                             (const float*)d_in[7], (const float*)d_in[8]};
    const float* w1  = (const float*)d_in[9];
    const float* b1  = (const float*)d_in[10];
    const float* g1  = (const float*)d_in[11];
    const float* be1 = (const float*)d_in[12];
    const float* w2  = (const float*)d_in[13];
    const float* b2  = (const float*)d_in[14];
    const float* g2  = (const float*)d_in[15];
    const float* be2 = (const float*)d_in[16];
    const float* w3a[4] = {(const float*)d_in[17], (const float*)d_in[19],
                           (const float*)d_in[21], (const float*)d_in[23]};
    const float* b3a[4] = {(const float*)d_in[18], (const float*)d_in[20],
                           (const float*)d_in[22], (const float*)d_in[24]};
    const float* ks0 = (const float*)d_in[25];
    const float* ks1 = (const float*)d_in[26];
    float* out = (float*)d_out;

    char*      ws    = (char*)d_ws;
    _Float16*  WT    = (_Float16*)ws;
    float*     stats = (float*)(ws + ST_BYTE);
    float*     dInv  = (float*)(ws + DI_BYTE);
    __half*    Sall  = (__half*)(ws + S_BYTE);
    _Float16*  w2h   = (_Float16*)(ws + W2H_BYTE);

    k0_prep<<<1164, 256, 0, stream>>>(w1, b1, nmask, x0, x1, ks0, ks1, w2,
                                      w3a[0], b3a[0], w3a[1], b3a[1],
                                      w3a[2], b3a[2], w3a[3], b3a[3],
                                      dInv, out, stats, WT, w2h);

    k1_mfma<<<dim3(384, 4), 256, 0, stream>>>(rel, w1, b1, g1, be1, b2, g2, be2, stats, ws);

    k2a<0,0><<<NN, 256, 0, stream>>>(x0, nidx, nmask, basis[0],
                                     (const __half*)(ws + H2OFF[0]), stats, Sall + SOFFS[0]);
    k2a<0,1><<<NN, 256, 0, stream>>>(x0, nidx, nmask, basis[1],
                                     (const __half*)(ws + H2OFF[1]), stats, Sall + SOFFS[1]);
    k2a<1,0><<<NN, 256, 0, stream>>>(x1, nidx, nmask, basis[2],
                                     (const __half*)(ws + H2OFF[2]), stats, Sall + SOFFS[2]);
    k2a<1,1><<<NN, 256, 0, stream>>>(x1, nidx, nmask, basis[3],
                                     (const __half*)(ws + H2OFF[3]), stats, Sall + SOFFS[3]);

    k2b_mfma<<<256, 256, 0, stream>>>(ws, dInv, out);
}

// Round 7
// 194.991 us; speedup vs baseline: 2.3311x; 1.1394x over previous
//
#include <hip/hip_runtime.h>
#include <hip/hip_fp16.h>

// ConvSE3: B=1, N=512, J=48, M=16, MID=128, pairs (di,do) in {0,1}^2.
//   k0 : LN1 stats, mask probe, dInv, self-init, w3T->WT fp16 (padded), w2T fp16
//   k1 : radial MLP via MFMA 16x16x32 f16 -> h2 fp16
//   k2a: ONE dispatch, all pairs+n: EmT fp16 + h2T fp16 (LDS) -> S via MFMA
//   k2b: out[row,o] += S[row,:]*WT[o,:] via MFMA (m-tile/block, K-split x4 waves)
// R7: k2a S-GEMM moved to MFMA (last scalar GEMM); 4 k2a launches merged; ws
// regions fully disjoint (ws_size ~268 MB per fill counter - no aliasing needed).

#define EPSV 1e-5f
constexpr int NN  = 512;
constexpr int JJ  = 48;
constexpr int EE  = NN * JJ;   // 24576 edges

// ---- workspace layout (bytes) -------------------------------------------
constexpr size_t WTOFFS[4] = {0, 33280, 66560, 99840};        // halfs
constexpr size_t ST_BYTE = 398336;
constexpr size_t DI_BYTE = 398464;
constexpr size_t S_BYTE  = 401408;
constexpr size_t SOFFS[4] = {0, 1064960, 4259840, 5324800};   // halfs rel S_BYTE
constexpr size_t H2OFF[4] = {33554432, 39845888, 46137344, 52428800};  // bytes
constexpr size_t W2H_BYTE = 62914560;

typedef _Float16 f16_t;
typedef __attribute__((ext_vector_type(8))) _Float16 v8h;
typedef __attribute__((ext_vector_type(4))) float v4f;

// ---------------------------------------------------------------- k0
__global__ __launch_bounds__(256) void k0_prep(
    const float* __restrict__ w1, const float* __restrict__ b1,
    const void* __restrict__ nmask,
    const float* __restrict__ x0, const float* __restrict__ x1,
    const float* __restrict__ ks0, const float* __restrict__ ks1,
    const float* __restrict__ w2,
    const float* __restrict__ w3_00, const float* __restrict__ b3_00,
    const float* __restrict__ w3_01, const float* __restrict__ b3_01,
    const float* __restrict__ w3_10, const float* __restrict__ b3_10,
    const float* __restrict__ w3_11, const float* __restrict__ b3_11,
    float* __restrict__ dInv, float* __restrict__ out, float* __restrict__ stats,
    _Float16* __restrict__ WT, _Float16* __restrict__ w2h)
{
    const int t = threadIdx.x;
    if (blockIdx.x == 0) {
        const int p = t >> 6, lane = t & 63;
        const float w0 = w1[p*128 + lane],       b0 = b1[p*128 + lane];
        const float w1v = w1[p*128 + 64 + lane], b1v = b1[p*128 + 64 + lane];
        float sw = w0 + w1v, sb = b0 + b1v;
        float sww = w0*w0 + w1v*w1v, swb = w0*b0 + w1v*b1v, sbb = b0*b0 + b1v*b1v;
        for (int off = 32; off > 0; off >>= 1) {
            sw  += __shfl_down(sw, off);  sb  += __shfl_down(sb, off);
            sww += __shfl_down(sww, off); swb += __shfl_down(swb, off);
            sbb += __shfl_down(sbb, off);
        }
        if (lane == 0) {
            const float wbar = sw*(1.f/128.f), bbar = sb*(1.f/128.f);
            stats[p*8+0] = wbar; stats[p*8+1] = bbar;
            stats[p*8+2] = sww*(1.f/128.f) - wbar*wbar;
            stats[p*8+3] = swb*(1.f/128.f) - wbar*bbar;
            stats[p*8+4] = sbb*(1.f/128.f) - bbar*bbar;
        }
        return;
    }
    if (blockIdx.x == 1) {
        __shared__ int flag;
        if (t == 0) flag = 0;
        __syncthreads();
        const int* m32 = (const int*)nmask;
        int bad = 0;
        for (int i = t; i < EE/4; i += 256) if ((unsigned)m32[i] > 1u) bad = 1;
        if (bad) flag = 1;
        __syncthreads();
        const int useU8 = flag;
        if (t == 0) stats[30] = useU8 ? 1.f : 0.f;
        for (int n = t; n < NN; n += 256) {
            float s = 0.f;
            if (useU8) {
                const unsigned char* m8 = (const unsigned char*)nmask;
                for (int j = 0; j < JJ; ++j) s += m8[n*JJ + j] ? 1.f : 0.f;
            } else {
                for (int j = 0; j < JJ; ++j) s += m32[n*JJ + j] ? 1.f : 0.f;
            }
            dInv[n] = 1.f / s;
        }
        return;
    }
    if (blockIdx.x < 130) {              // self-interaction init
        const int gid = (blockIdx.x - 2) * 256 + t;
        const int d = gid & 3, o = (gid >> 2) & 15, n = gid >> 6;
        float acc = 0.f;
        if (d == 0) {
            #pragma unroll
            for (int i = 0; i < 16; ++i) acc += ks0[o*16+i] * x0[n*16+i];
        } else {
            const int u = d - 1;
            #pragma unroll
            for (int i = 0; i < 16; ++i) acc += ks1[o*16+i] * x1[(n*16+i)*3 + u];
        }
        out[gid] = acc;
        return;
    }
    if (blockIdx.x < 908) {              // WT: [o][CKP] fp16, zero-padded tail
        const int gid = (blockIdx.x - 130) * 256 + t;   // [0, 199168)
        if (gid >= 199168) return;
        int p, base;
        if      (gid < 33280)  { p = 0; base = 0; }
        else if (gid < 66560)  { p = 1; base = 33280; }
        else if (gid < 99840)  { p = 2; base = 66560; }
        else                   { p = 3; base = 99840; }
        const int KF = (p == 3) ? 48 : 16;
        const int CK = 129*KF, CKP = CK + 16;
        const int e = gid - base;
        const int o = e / CKP, ck = e - o*CKP;
        float v = 0.f;
        if (ck < CK) {
            const int c = ck / KF, k = ck - c*KF;
            const float* w3 = (p==0) ? w3_00 : (p==1) ? w3_01 : (p==2) ? w3_10 : w3_11;
            const float* b3 = (p==0) ? b3_00 : (p==1) ? b3_01 : (p==2) ? b3_10 : b3_11;
            v = (c < 128) ? w3[(size_t)c*(16*KF) + o*KF + k] : b3[o*KF + k];
        }
        WT[base + (size_t)o*CKP + ck] = (_Float16)v;
        return;
    }
    // w2 transpose -> fp16: w2h[p][c][k] = w2[p][k][c]
    const int gid = (blockIdx.x - 908) * 256 + t;       // [0, 65536)
    const int p = gid >> 14, rem = gid & 16383;
    const int c = rem >> 7, k = rem & 127;
    w2h[gid] = (_Float16)w2[p*16384 + k*128 + c];
}

// ---------------------------------------------------------------- k1: radial MLP (MFMA)
__global__ __launch_bounds__(256, 2) void k1_mfma(
    const float* __restrict__ rel,
    const float* __restrict__ w1, const float* __restrict__ b1,
    const float* __restrict__ g1, const float* __restrict__ be1,
    const float* __restrict__ b2, const float* __restrict__ g2,
    const float* __restrict__ be2,
    const float* __restrict__ stats, char* __restrict__ ws)
{
    const int p  = blockIdx.y;
    const int e0 = blockIdx.x * 64;
    const int t  = threadIdx.x;
    const _Float16* __restrict__ w2h = (const _Float16*)(ws + W2H_BYTE) + (size_t)p*16384;
    _Float16* __restrict__ h2out = (_Float16*)(ws + H2OFF[p]);

    __shared__ __align__(16) _Float16 h1L[64*136];
    __shared__ __align__(16) _Float16 w2L[128*136];
    __shared__ float dsh[64];
    __shared__ float pb[384];

    if (t < 64) dsh[t] = rel[e0 + t];
    if (t < 128) {
        pb[t]       = b2[p*128 + t];
        pb[128 + t] = g2[p*128 + t];
        pb[256 + t] = be2[p*128 + t];
    }
    for (int i = t; i < 2048; i += 256) {
        const int c = i >> 4, off = (i & 15) * 8;
        *(float4*)(w2L + c*136 + off) = *(const float4*)(w2h + c*128 + off);
    }
    __syncthreads();

    {   // h1 = relu(LN1(d*w1+b1)) analytic
        const int cin = t & 127, eh = t >> 7;
        const float w  = w1[p*128 + cin], b  = b1[p*128 + cin];
        const float g  = g1[p*128 + cin], be = be1[p*128 + cin];
        const float wbar = stats[p*8+0], bbar = stats[p*8+1];
        const float Cw = stats[p*8+2], Cwb = stats[p*8+3], Cb = stats[p*8+4];
        for (int e = eh*32; e < eh*32 + 32; ++e) {
            const float d   = dsh[e];
            const float mu  = fmaf(d, wbar, bbar);
            const float var = fmaf(d*d, Cw, fmaf(2.f*d, Cwb, Cb));
            const float y   = fmaf((fmaf(d, w, b) - mu) * rsqrtf(var + EPSV), g, be);
            h1L[e*136 + cin] = (_Float16)fmaxf(y, 0.f);
        }
    }
    __syncthreads();

    const int l = t & 63, wv = t >> 6;
    const int q = l >> 4, c16 = l & 15;
    const int m0 = wv * 16;
    v4f acc[8];
    #pragma unroll
    for (int nt = 0; nt < 8; ++nt) { acc[nt][0]=0.f; acc[nt][1]=0.f; acc[nt][2]=0.f; acc[nt][3]=0.f; }

    #pragma unroll
    for (int ks = 0; ks < 4; ++ks) {
        const int k0 = ks*32 + q*8;
        const v8h a = *(const v8h*)(h1L + (m0 + c16)*136 + k0);
        #pragma unroll
        for (int nt = 0; nt < 8; ++nt) {
            const v8h bf = *(const v8h*)(w2L + (nt*16 + c16)*136 + k0);
            acc[nt] = __builtin_amdgcn_mfma_f32_16x16x32_f16(a, bf, acc[nt], 0, 0, 0);
        }
    }

    float bl[8], gl[8], bel[8];
    #pragma unroll
    for (int nt = 0; nt < 8; ++nt) {
        bl[nt]  = pb[nt*16 + c16];
        gl[nt]  = pb[128 + nt*16 + c16];
        bel[nt] = pb[256 + nt*16 + c16];
    }
    #pragma unroll
    for (int nt = 0; nt < 8; ++nt)
        #pragma unroll
        for (int r = 0; r < 4; ++r) acc[nt][r] += bl[nt];

    #pragma unroll
    for (int r = 0; r < 4; ++r) {
        float s = 0.f, qq = 0.f;
        #pragma unroll
        for (int nt = 0; nt < 8; ++nt) { const float v = acc[nt][r]; s += v; qq += v*v; }
        #pragma unroll
        for (int m = 1; m < 16; m <<= 1) { s += __shfl_xor(s, m); qq += __shfl_xor(qq, m); }
        const float mu = s * (1.f/128.f);
        const float rs = rsqrtf(qq*(1.f/128.f) - mu*mu + EPSV);
        const int e = m0 + q*4 + r;
        #pragma unroll
        for (int nt = 0; nt < 8; ++nt) {
            const float v = fmaxf(fmaf((acc[nt][r] - mu)*rs, gl[nt], bel[nt]), 0.f);
            h1L[e*136 + nt*16 + c16] = (_Float16)v;
        }
    }
    __syncthreads();

    for (int i = t; i < 1024; i += 256) {
        const int e = i >> 4, off = (i & 15) * 8;
        *(float4*)(h2out + (size_t)(e0 + e)*128 + off) = *(const float4*)(h1L + e*136 + off);
    }
}

// ---------------------------------------------------------------- k2a (MFMA), one block per (pair,n)
template<int DI, int DO>
__device__ __forceinline__ void k2a_dev(
    const int n, const float* __restrict__ xsrc,
    const int* __restrict__ nidx, const void* __restrict__ nmaskv,
    const float* __restrict__ basis, const _Float16* __restrict__ h2w,
    const float* __restrict__ stats, __half* __restrict__ Sp, char* smem)
{
    constexpr int V  = 2*DI + 1;
    constexpr int U  = 2*DO + 1;
    constexpr int F  = 2*(DI < DO ? DI : DO) + 1;
    constexpr int KF = 16*F;
    constexpr int Q  = 16*U*F;          // q = u*KF + k ; multiple of 16
    constexpr int BP = U*V*F;
    constexpr int XW = 16*V;
    constexpr int CK = 129*KF;
    constexpr int CKP = CK + 16;
    constexpr int MT = Q/16;            // q-tiles
    constexpr int NT = 9;               // c-tiles (144 rows, 129 valid)

    _Float16* h2s = (_Float16*)smem;                    // [48][136] staging
    _Float16* h2T = (_Float16*)(smem + 13056);          // [144][72]
    _Float16* EmT = (_Float16*)(smem + 33792);          // [Q][72]
    float* xg   = (float*)(smem + 33792 + Q*144);       // [48][XW]
    float* basL = xg + 48*XW;                           // [48][BP]
    int*   idxL = (int*)(basL + 48*BP);
    float* mjf  = (float*)(idxL + 48);

    const int t = threadIdx.x;

    // phase A: zero h2T+EmT (contiguous), load idx/mask, S K-pad
    for (int i = t; i < (144*72 + Q*72)/2; i += 256)
        ((unsigned*)h2T)[i] = 0u;
    if (t < 48) {
        idxL[t] = nidx[n*JJ + t];
        const int useU8 = (stats[30] != 0.f);
        const int mv = useU8 ? (int)((const unsigned char*)nmaskv)[n*JJ + t]
                             : ((const int*)nmaskv)[n*JJ + t];
        mjf[t] = mv ? 1.f : 0.f;
    }
    if (t >= 64 && t < 64 + U*16) {
        const int i2 = t - 64;
        Sp[(size_t)(n*U + (i2 >> 4))*CKP + CK + (i2 & 15)] = __float2half(0.f);
    }
    __syncthreads();

    // loads (idxL ready)
    for (int e = t; e < 48*XW; e += 256) {
        const int j = e / XW, r = e - j*XW;
        xg[e] = xsrc[idxL[j]*XW + r];
    }
    for (int e = t; e < 48*BP; e += 256)
        basL[e] = basis[(size_t)n*48*BP + e];
    for (int i = t; i < 768; i += 256) {          // h2 stage, coalesced b128
        const int j = i >> 4, c8 = (i & 15) * 8;
        *(float4*)(h2s + j*136 + c8) = *(const float4*)(h2w + (size_t)(n*JJ + j)*128 + c8);
    }
    __syncthreads();

    // phase B: transpose h2 -> h2T ; ones row (b3) ; EmT
    for (int i = t; i < 6144; i += 256) {
        const int c = i & 127, j = i >> 7;
        h2T[c*72 + j] = h2s[j*136 + c];
    }
    if (t < 48) h2T[128*72 + t] = (_Float16)1.f;
    for (int e = t; e < Q*48; e += 256) {
        const int q = e / 48, j = e - q*48;
        const int u = q / KF, k = q - u*KF, i = k / F, f = k - i*F;
        float a = 0.f;
        #pragma unroll
        for (int v = 0; v < V; ++v)
            a = fmaf(basL[j*BP + (u*V + v)*F + f], xg[j*XW + i*V + v], a);
        EmT[q*72 + j] = (_Float16)(mjf[j] * a);
    }
    __syncthreads();

    // phase C: D[q][c] = sum_j EmT[q][j]*h2T[c][j] via MFMA; store packed uint2
    const int wv = t >> 6, l = t & 63;
    const int q8 = l >> 4, l15 = l & 15;
    for (int tt = wv; tt < MT*NT; tt += 4) {
        const int mt = tt / NT, nt = tt - mt*NT;
        v4f acc; acc[0]=0.f; acc[1]=0.f; acc[2]=0.f; acc[3]=0.f;
        #pragma unroll
        for (int ks = 0; ks < 2; ++ks) {
            const v8h a = *(const v8h*)(EmT + (mt*16 + l15)*72 + ks*32 + q8*8);
            const v8h b = *(const v8h*)(h2T + (nt*16 + l15)*72 + ks*32 + q8*8);
            acc = __builtin_amdgcn_mfma_f32_16x16x32_f16(a, b, acc, 0, 0, 0);
        }
        const int c = nt*16 + l15;
        if (c <= 128) {
            const int q0 = mt*16 + q8*4;
            const int u = q0 / KF, k0 = q0 - u*KF;
            union { uint2 uu; _Float16 h[4]; } pk;
            #pragma unroll
            for (int r = 0; r < 4; ++r) pk.h[r] = (_Float16)acc[r];
            *(uint2*)(Sp + (size_t)(n*U + u)*CKP + (size_t)c*KF + k0) = pk.uu;
        }
    }
}

__global__ __launch_bounds__(256, 2) void k2a_all(
    const float* __restrict__ x0, const float* __restrict__ x1,
    const int* __restrict__ nidx, const void* __restrict__ nmask,
    const float* __restrict__ b00, const float* __restrict__ b01,
    const float* __restrict__ b10, const float* __restrict__ b11,
    const float* __restrict__ stats, char* __restrict__ ws)
{
    __shared__ __align__(16) char smem[69376];
    const int pair = blockIdx.x >> 9, n = blockIdx.x & 511;
    __half* Sall = (__half*)(ws + S_BYTE);
    switch (pair) {
    case 0: k2a_dev<0,0>(n, x0, nidx, nmask, b00, (const _Float16*)(ws + H2OFF[0]), stats, Sall + SOFFS[0], smem); break;
    case 1: k2a_dev<0,1>(n, x0, nidx, nmask, b01, (const _Float16*)(ws + H2OFF[1]), stats, Sall + SOFFS[1], smem); break;
    case 2: k2a_dev<1,0>(n, x1, nidx, nmask, b10, (const _Float16*)(ws + H2OFF[2]), stats, Sall + SOFFS[2], smem); break;
    default: k2a_dev<1,1>(n, x1, nidx, nmask, b11, (const _Float16*)(ws + H2OFF[3]), stats, Sall + SOFFS[3], smem); break;
    }
}

// ---------------------------------------------------------------- k2b: MFMA GEMM out += S * WT^T
__global__ __launch_bounds__(256) void k2b_mfma(
    const char* __restrict__ wsbase, const float* __restrict__ dInv,
    float* __restrict__ out)
{
    const int b = blockIdx.x;
    int pair, mt;
    if (b < 32)       { pair = 0; mt = b; }
    else if (b < 128) { pair = 1; mt = b - 32; }
    else if (b < 160) { pair = 2; mt = b - 128; }
    else              { pair = 3; mt = b - 160; }
    const int U     = (pair == 1 || pair == 3) ? 3 : 1;
    const int dbase = (U == 3) ? 1 : 0;
    const int CKP   = (pair == 3) ? 6208 : 2080;
    const int NK    = CKP >> 5;
    const _Float16* S  = (const _Float16*)(wsbase + S_BYTE) + SOFFS[pair];
    const _Float16* WT = (const _Float16*)wsbase + WTOFFS[pair];

    const int t = threadIdx.x;
    const int wv = t >> 6, l = t & 63;
    const int q = l >> 4, c16 = l & 15;
    const int KC = (NK + 3) >> 2;
    const int k_lo = wv * KC;
    const int k_hi = (k_lo + KC < NK) ? (k_lo + KC) : NK;

    const int row0 = mt * 16;
    const _Float16* sp = S  + (size_t)(row0 + c16) * CKP + q*8;
    const _Float16* wp = WT + (size_t)c16 * CKP + q*8;

    v4f acc; acc[0]=0.f; acc[1]=0.f; acc[2]=0.f; acc[3]=0.f;
    #pragma unroll 4
    for (int ks = k_lo; ks < k_hi; ++ks) {
        const v8h a  = *(const v8h*)(sp + ks*32);
        const v8h bf = *(const v8h*)(wp + ks*32);
        acc = __builtin_amdgcn_mfma_f32_16x16x32_f16(a, bf, acc, 0, 0, 0);
    }

    __shared__ float red[4][16][16];
    #pragma unroll
    for (int r = 0; r < 4; ++r) red[wv][q*4 + r][c16] = acc[r];
    __syncthreads();

    {
        const int r16 = t >> 4, o = t & 15;
        const float v = red[0][r16][o] + red[1][r16][o] + red[2][r16][o] + red[3][r16][o];
        const int row = row0 + r16;
        int n, u;
        if (U == 1) { n = row; u = 0; }
        else        { n = row / 3; u = row - n*3; }
        atomicAdd(out + (size_t)(n*16 + o)*4 + (dbase ? 1 + u : 0), v * dInv[n]);
    }
}

// ---------------------------------------------------------------- launch
extern "C" void kernel_launch(void* const* d_in, const int* in_sizes, int n_in,
                              void* d_out, int out_size, void* d_ws, size_t ws_size,
                              hipStream_t stream)
{
    const float* x0    = (const float*)d_in[0];
    const float* x1    = (const float*)d_in[1];
    const float* rel   = (const float*)d_in[2];
    const int*   nidx  = (const int*)d_in[3];
    const void*  nmask = d_in[4];
    const float* basis[4] = {(const float*)d_in[5], (const float*)d_in[6],
                             (const float*)d_in[7], (const float*)d_in[8]};
    const float* w1  = (const float*)d_in[9];
    const float* b1  = (const float*)d_in[10];
    const float* g1  = (const float*)d_in[11];
    const float* be1 = (const float*)d_in[12];
    const float* w2  = (const float*)d_in[13];
    const float* b2  = (const float*)d_in[14];
    const float* g2  = (const float*)d_in[15];
    const float* be2 = (const float*)d_in[16];
    const float* w3a[4] = {(const float*)d_in[17], (const float*)d_in[19],
                           (const float*)d_in[21], (const float*)d_in[23]};
    const float* b3a[4] = {(const float*)d_in[18], (const float*)d_in[20],
                           (const float*)d_in[22], (const float*)d_in[24]};
    const float* ks0 = (const float*)d_in[25];
    const float* ks1 = (const float*)d_in[26];
    float* out = (float*)d_out;

    char*      ws    = (char*)d_ws;
    _Float16*  WT    = (_Float16*)ws;
    float*     stats = (float*)(ws + ST_BYTE);
    float*     dInv  = (float*)(ws + DI_BYTE);
    _Float16*  w2h   = (_Float16*)(ws + W2H_BYTE);

    k0_prep<<<1164, 256, 0, stream>>>(w1, b1, nmask, x0, x1, ks0, ks1, w2,
                                      w3a[0], b3a[0], w3a[1], b3a[1],
                                      w3a[2], b3a[2], w3a[3], b3a[3],
                                      dInv, out, stats, WT, w2h);

    k1_mfma<<<dim3(384, 4), 256, 0, stream>>>(rel, w1, b1, g1, be1, b2, g2, be2, stats, ws);

    k2a_all<<<2048, 256, 0, stream>>>(x0, x1, nidx, nmask,
                                      basis[0], basis[1], basis[2], basis[3], stats, ws);

    k2b_mfma<<<256, 256, 0, stream>>>(ws, dInv, out);
}

// Round 9
// 194.831 us; speedup vs baseline: 2.3330x; 1.0008x over previous
//
#include <hip/hip_runtime.h>
#include <hip/hip_fp16.h>

// ConvSE3: B=1, N=512, J=48, M=16, MID=128, pairs (di,do) in {0,1}^2.
//   k0 : LN1 stats, mask probe, dInv, self-init, w3T->WT fp16, w2T fp16, h2T ones-row
//   k1 : radial MLP via MFMA -> h2T fp16 [c][edge] (transposed in LDS via D-layout packing)
//   k2a: ONE dispatch: EmT fp16 (LDS) x h2T (global, L1-hot) via MFMA 16x16x16 -> S
//   k2b: out[row,o] += S[row,:]*WT[o,:] via MFMA
// R9: fix builtin spelling: legacy K=16 shape is __builtin_amdgcn_mfma_f32_16x16x16f16
// (no underscore before f16) on gfx950/ROCm; R8 logic otherwise unchanged.

#define EPSV 1e-5f
constexpr int NN  = 512;
constexpr int JJ  = 48;
constexpr int EE  = NN * JJ;   // 24576 edges

// ---- workspace layout (bytes) -------------------------------------------
constexpr size_t WTOFFS[4] = {0, 33280, 66560, 99840};        // halfs
constexpr size_t ST_BYTE = 398336;
constexpr size_t DI_BYTE = 398464;
constexpr size_t S_BYTE  = 401408;
constexpr size_t SOFFS[4] = {0, 1064960, 4259840, 5324800};   // halfs rel S_BYTE
constexpr size_t H2T_BYTE  = 33554432;                        // h2T [144][EE] per pair
constexpr size_t H2T_PAIRB = 7372800;                         // bytes per pair slab
constexpr size_t W2H_BYTE  = 67108864;

typedef _Float16 f16_t;
typedef __attribute__((ext_vector_type(4))) _Float16 v4h;
typedef __attribute__((ext_vector_type(8))) _Float16 v8h;
typedef __attribute__((ext_vector_type(4))) float v4f;

// ---------------------------------------------------------------- k0
__global__ __launch_bounds__(256) void k0_prep(
    const float* __restrict__ w1, const float* __restrict__ b1,
    const void* __restrict__ nmask,
    const float* __restrict__ x0, const float* __restrict__ x1,
    const float* __restrict__ ks0, const float* __restrict__ ks1,
    const float* __restrict__ w2,
    const float* __restrict__ w3_00, const float* __restrict__ b3_00,
    const float* __restrict__ w3_01, const float* __restrict__ b3_01,
    const float* __restrict__ w3_10, const float* __restrict__ b3_10,
    const float* __restrict__ w3_11, const float* __restrict__ b3_11,
    float* __restrict__ dInv, float* __restrict__ out, float* __restrict__ stats,
    _Float16* __restrict__ WT, _Float16* __restrict__ w2h,
    _Float16* __restrict__ h2t0)
{
    const int t = threadIdx.x;
    if (blockIdx.x == 0) {
        const int p = t >> 6, lane = t & 63;
        const float w0 = w1[p*128 + lane],       b0 = b1[p*128 + lane];
        const float w1v = w1[p*128 + 64 + lane], b1v = b1[p*128 + 64 + lane];
        float sw = w0 + w1v, sb = b0 + b1v;
        float sww = w0*w0 + w1v*w1v, swb = w0*b0 + w1v*b1v, sbb = b0*b0 + b1v*b1v;
        for (int off = 32; off > 0; off >>= 1) {
            sw  += __shfl_down(sw, off);  sb  += __shfl_down(sb, off);
            sww += __shfl_down(sww, off); swb += __shfl_down(swb, off);
            sbb += __shfl_down(sbb, off);
        }
        if (lane == 0) {
            const float wbar = sw*(1.f/128.f), bbar = sb*(1.f/128.f);
            stats[p*8+0] = wbar; stats[p*8+1] = bbar;
            stats[p*8+2] = sww*(1.f/128.f) - wbar*wbar;
            stats[p*8+3] = swb*(1.f/128.f) - wbar*bbar;
            stats[p*8+4] = sbb*(1.f/128.f) - bbar*bbar;
        }
        return;
    }
    if (blockIdx.x == 1) {
        __shared__ int flag;
        if (t == 0) flag = 0;
        __syncthreads();
        const int* m32 = (const int*)nmask;
        int bad = 0;
        for (int i = t; i < EE/4; i += 256) if ((unsigned)m32[i] > 1u) bad = 1;
        if (bad) flag = 1;
        __syncthreads();
        const int useU8 = flag;
        if (t == 0) stats[30] = useU8 ? 1.f : 0.f;
        for (int n = t; n < NN; n += 256) {
            float s = 0.f;
            if (useU8) {
                const unsigned char* m8 = (const unsigned char*)nmask;
                for (int j = 0; j < JJ; ++j) s += m8[n*JJ + j] ? 1.f : 0.f;
            } else {
                for (int j = 0; j < JJ; ++j) s += m32[n*JJ + j] ? 1.f : 0.f;
            }
            dInv[n] = 1.f / s;
        }
        return;
    }
    if (blockIdx.x < 130) {              // self-interaction init
        const int gid = (blockIdx.x - 2) * 256 + t;
        const int d = gid & 3, o = (gid >> 2) & 15, n = gid >> 6;
        float acc = 0.f;
        if (d == 0) {
            #pragma unroll
            for (int i = 0; i < 16; ++i) acc += ks0[o*16+i] * x0[n*16+i];
        } else {
            const int u = d - 1;
            #pragma unroll
            for (int i = 0; i < 16; ++i) acc += ks1[o*16+i] * x1[(n*16+i)*3 + u];
        }
        out[gid] = acc;
        return;
    }
    if (blockIdx.x < 908) {              // WT: [o][CKP] fp16, zero-padded tail
        const int gid = (blockIdx.x - 130) * 256 + t;   // [0, 199168)
        if (gid >= 199168) return;
        int p, base;
        if      (gid < 33280)  { p = 0; base = 0; }
        else if (gid < 66560)  { p = 1; base = 33280; }
        else if (gid < 99840)  { p = 2; base = 66560; }
        else                   { p = 3; base = 99840; }
        const int KF = (p == 3) ? 48 : 16;
        const int CK = 129*KF, CKP = CK + 16;
        const int e = gid - base;
        const int o = e / CKP, ck = e - o*CKP;
        float v = 0.f;
        if (ck < CK) {
            const int c = ck / KF, k = ck - c*KF;
            const float* w3 = (p==0) ? w3_00 : (p==1) ? w3_01 : (p==2) ? w3_10 : w3_11;
            const float* b3 = (p==0) ? b3_00 : (p==1) ? b3_01 : (p==2) ? b3_10 : b3_11;
            v = (c < 128) ? w3[(size_t)c*(16*KF) + o*KF + k] : b3[o*KF + k];
        }
        WT[base + (size_t)o*CKP + ck] = (_Float16)v;
        return;
    }
    if (blockIdx.x < 1164) {
        // w2 transpose -> fp16: w2h[p][c][k] = w2[p][k][c]
        const int gid = (blockIdx.x - 908) * 256 + t;   // [0, 65536)
        const int p = gid >> 14, rem = gid & 16383;
        const int c = rem >> 7, k = rem & 127;
        w2h[gid] = (_Float16)w2[p*16384 + k*128 + c];
        return;
    }
    // h2T ones row (c=128, the b3 row) per pair: 4 x EE halfs, 8 per thread
    const int gid = (blockIdx.x - 1164) * 256 + t;      // [0, 12288)
    const int p = gid / 3072, r8 = gid - p*3072;
    union { float4 f; _Float16 h[8]; } one;
    #pragma unroll
    for (int i = 0; i < 8; ++i) one.h[i] = (_Float16)1.f;
    *(float4*)(h2t0 + (size_t)p*(H2T_PAIRB/2) + (size_t)128*EE + r8*8) = one.f;
}

// ---------------------------------------------------------------- k1: radial MLP (MFMA) -> h2T
__global__ __launch_bounds__(256, 2) void k1_mfma(
    const float* __restrict__ rel,
    const float* __restrict__ w1, const float* __restrict__ b1,
    const float* __restrict__ g1, const float* __restrict__ be1,
    const float* __restrict__ b2, const float* __restrict__ g2,
    const float* __restrict__ be2,
    const float* __restrict__ stats, char* __restrict__ ws)
{
    const int p  = blockIdx.y;
    const int e0 = blockIdx.x * 64;
    const int t  = threadIdx.x;
    const _Float16* __restrict__ w2h = (const _Float16*)(ws + W2H_BYTE) + (size_t)p*16384;
    _Float16* __restrict__ h2Tg = (_Float16*)(ws + H2T_BYTE + (size_t)p*H2T_PAIRB);

    __shared__ __align__(16) _Float16 h1L[64*136];
    __shared__ __align__(16) _Float16 w2L[128*136];   // phase2 B; then overlaid by h1T[128][72]
    __shared__ float dsh[64];
    __shared__ float pb[384];
    _Float16* h1T = w2L;                              // [c][edge-in-block], stride 72

    if (t < 64) dsh[t] = rel[e0 + t];
    if (t < 128) {
        pb[t]       = b2[p*128 + t];
        pb[128 + t] = g2[p*128 + t];
        pb[256 + t] = be2[p*128 + t];
    }
    for (int i = t; i < 2048; i += 256) {
        const int c = i >> 4, off = (i & 15) * 8;
        *(float4*)(w2L + c*136 + off) = *(const float4*)(w2h + c*128 + off);
    }
    __syncthreads();

    {   // h1 = relu(LN1(d*w1+b1)) analytic
        const int cin = t & 127, eh = t >> 7;
        const float w  = w1[p*128 + cin], b  = b1[p*128 + cin];
        const float g  = g1[p*128 + cin], be = be1[p*128 + cin];
        const float wbar = stats[p*8+0], bbar = stats[p*8+1];
        const float Cw = stats[p*8+2], Cwb = stats[p*8+3], Cb = stats[p*8+4];
        for (int e = eh*32; e < eh*32 + 32; ++e) {
            const float d   = dsh[e];
            const float mu  = fmaf(d, wbar, bbar);
            const float var = fmaf(d*d, Cw, fmaf(2.f*d, Cwb, Cb));
            const float y   = fmaf((fmaf(d, w, b) - mu) * rsqrtf(var + EPSV), g, be);
            h1L[e*136 + cin] = (_Float16)fmaxf(y, 0.f);
        }
    }
    __syncthreads();

    const int l = t & 63, wv = t >> 6;
    const int q = l >> 4, c16 = l & 15;
    const int m0 = wv * 16;
    v4f acc[8];
    #pragma unroll
    for (int nt = 0; nt < 8; ++nt) { acc[nt][0]=0.f; acc[nt][1]=0.f; acc[nt][2]=0.f; acc[nt][3]=0.f; }

    #pragma unroll
    for (int ks = 0; ks < 4; ++ks) {
        const int k0 = ks*32 + q*8;
        const v8h a = *(const v8h*)(h1L + (m0 + c16)*136 + k0);
        #pragma unroll
        for (int nt = 0; nt < 8; ++nt) {
            const v8h bf = *(const v8h*)(w2L + (nt*16 + c16)*136 + k0);
            acc[nt] = __builtin_amdgcn_mfma_f32_16x16x32_f16(a, bf, acc[nt], 0, 0, 0);
        }
    }
    __syncthreads();   // w2L reads done; h1T overlay becomes safe

    float bl[8], gl[8], bel[8];
    #pragma unroll
    for (int nt = 0; nt < 8; ++nt) {
        bl[nt]  = pb[nt*16 + c16];
        gl[nt]  = pb[128 + nt*16 + c16];
        bel[nt] = pb[256 + nt*16 + c16];
    }
    #pragma unroll
    for (int nt = 0; nt < 8; ++nt)
        #pragma unroll
        for (int r = 0; r < 4; ++r) acc[nt][r] += bl[nt];

    float muR[4], rsR[4];
    #pragma unroll
    for (int r = 0; r < 4; ++r) {
        float s = 0.f, qq = 0.f;
        #pragma unroll
        for (int nt = 0; nt < 8; ++nt) { const float v = acc[nt][r]; s += v; qq += v*v; }
        #pragma unroll
        for (int m = 1; m < 16; m <<= 1) { s += __shfl_xor(s, m); qq += __shfl_xor(qq, m); }
        muR[r] = s * (1.f/128.f);
        rsR[r] = rsqrtf(qq*(1.f/128.f) - muR[r]*muR[r] + EPSV);
    }
    // pack 4 consecutive edges per (cout) -> 8B store into h1T[c][e] (min-conflict)
    #pragma unroll
    for (int nt = 0; nt < 8; ++nt) {
        union { uint2 uu; _Float16 h[4]; } pk;
        #pragma unroll
        for (int r = 0; r < 4; ++r)
            pk.h[r] = (_Float16)fmaxf(fmaf((acc[nt][r] - muR[r])*rsR[r], gl[nt], bel[nt]), 0.f);
        *(uint2*)(h1T + (nt*16 + c16)*72 + m0 + q*4) = pk.uu;
    }
    __syncthreads();

    for (int i = t; i < 1024; i += 256) {             // transposed global write, b128
        const int c = i >> 3, off = (i & 7) * 8;
        *(float4*)(h2Tg + (size_t)c*EE + e0 + off) = *(const float4*)(h1T + c*72 + off);
    }
}

// ---------------------------------------------------------------- k2a (MFMA, global B), one block per (pair,n)
template<int DI, int DO>
__device__ __forceinline__ void k2a_dev(
    const int n, const float* __restrict__ xsrc,
    const int* __restrict__ nidx, const void* __restrict__ nmaskv,
    const float* __restrict__ basis, const _Float16* __restrict__ h2Tg,
    const float* __restrict__ stats, __half* __restrict__ Sp, char* smem)
{
    constexpr int V  = 2*DI + 1;
    constexpr int U  = 2*DO + 1;
    constexpr int F  = 2*(DI < DO ? DI : DO) + 1;
    constexpr int KF = 16*F;
    constexpr int Q  = 16*U*F;          // q = u*KF + i*F + f
    constexpr int BP = U*V*F;
    constexpr int XW = 16*V;
    constexpr int CK = 129*KF;
    constexpr int CKP = CK + 16;
    constexpr int MT = Q/16;
    constexpr int NT = 9;               // c-tiles: 144 rows (129 valid, rest garbage-masked)

    _Float16* EmT = (_Float16*)smem;                          // [Q][56] (48 used, 8 pad)
    float* xg   = (float*)(smem + Q*112);                     // [48][XW]
    float* basL = xg + 48*XW;                                 // [48*BP]
    int2*  lut  = (int2*)(basL + 48*BP);                      // [Q]
    int*   idxL = (int*)(lut + Q);
    float* mjf  = (float*)(idxL + 48);

    const int t = threadIdx.x;

    if (t < 48) {
        idxL[t] = nidx[n*JJ + t];
        const int useU8 = (stats[30] != 0.f);
        const int mv = useU8 ? (int)((const unsigned char*)nmaskv)[n*JJ + t]
                             : ((const int*)nmaskv)[n*JJ + t];
        mjf[t] = mv ? 1.f : 0.f;
    }
    if (t >= 64 && t < 64 + Q) {        // (u,i,f) LUT
        const int q2 = t - 64;
        const int u = q2 / KF, k = q2 - u*KF, i = k / F, f = k - i*F;
        lut[q2] = make_int2((u*V)*F + f, i*V);
    }
    if (t >= 208 && t < 208 + U*16) {   // S K-pad zero
        const int i2 = t - 208;
        Sp[(size_t)(n*U + (i2 >> 4))*CKP + CK + (i2 & 15)] = __float2half(0.f);
    }
    __syncthreads();

    for (int e = t; e < 48*XW; e += 256) {
        const int j = e / XW, r = e - j*XW;
        xg[e] = xsrc[idxL[j]*XW + r];
    }
    for (int e = t; e < 48*BP; e += 256)
        basL[e] = basis[(size_t)n*48*BP + e];
    __syncthreads();

    // EmT[q][j] = mjf[j] * sum_v basis[j][(u*V+v)*F+f] * xg[j][i*V+v]
    for (int e = t; e < Q*48; e += 256) {
        const int q2 = e / 48, j = e - q2*48;
        const int2 lu = lut[q2];
        float a = 0.f;
        #pragma unroll
        for (int v = 0; v < V; ++v)
            a = fmaf(basL[j*BP + lu.x + v*F], xg[j*XW + lu.y + v], a);
        EmT[q2*56 + j] = (_Float16)(mjf[j] * a);
    }
    __syncthreads();

    // S[c][q] = sum_j EmT[q][j] * h2T[c][j]  via mfma 16x16x16 (K=48 = 3 steps)
    const int wv = t >> 6, l = t & 63;
    const int q8 = l >> 4, l15 = l & 15;
    const _Float16* bbase = h2Tg + (size_t)l15*EE + n*48 + q8*4;
    for (int tt = wv; tt < MT*NT; tt += 4) {
        const int mt = tt / NT, nt = tt - mt*NT;
        v4f acc; acc[0]=0.f; acc[1]=0.f; acc[2]=0.f; acc[3]=0.f;
        #pragma unroll
        for (int ks = 0; ks < 3; ++ks) {
            const v4h a = *(const v4h*)(EmT + (mt*16 + l15)*56 + ks*16 + q8*4);
            const v4h b = *(const v4h*)(bbase + (size_t)nt*16*EE + ks*16);
            acc = __builtin_amdgcn_mfma_f32_16x16x16f16(a, b, acc, 0, 0, 0);
        }
        const int c = nt*16 + l15;
        if (c <= 128) {
            const int q0 = mt*16 + q8*4;
            const int u = q0 / KF, k0 = q0 - u*KF;
            union { uint2 uu; _Float16 h[4]; } pk;
            #pragma unroll
            for (int r = 0; r < 4; ++r) pk.h[r] = (_Float16)acc[r];
            *(uint2*)(Sp + (size_t)(n*U + u)*CKP + (size_t)c*KF + k0) = pk.uu;
        }
    }
}

__global__ __launch_bounds__(256, 4) void k2a_all(
    const float* __restrict__ x0, const float* __restrict__ x1,
    const int* __restrict__ nidx, const void* __restrict__ nmask,
    const float* __restrict__ b00, const float* __restrict__ b01,
    const float* __restrict__ b10, const float* __restrict__ b11,
    const float* __restrict__ stats, char* __restrict__ ws)
{
    __shared__ __align__(16) char smem[32768];
    const int pair = blockIdx.x >> 9, n = blockIdx.x & 511;
    __half* Sall = (__half*)(ws + S_BYTE);
    const char* h2t = ws + H2T_BYTE;
    switch (pair) {
    case 0: k2a_dev<0,0>(n, x0, nidx, nmask, b00, (const _Float16*)(h2t + 0*H2T_PAIRB), stats, Sall + SOFFS[0], smem); break;
    case 1: k2a_dev<0,1>(n, x0, nidx, nmask, b01, (const _Float16*)(h2t + 1*H2T_PAIRB), stats, Sall + SOFFS[1], smem); break;
    case 2: k2a_dev<1,0>(n, x1, nidx, nmask, b10, (const _Float16*)(h2t + 2*H2T_PAIRB), stats, Sall + SOFFS[2], smem); break;
    default: k2a_dev<1,1>(n, x1, nidx, nmask, b11, (const _Float16*)(h2t + 3*H2T_PAIRB), stats, Sall + SOFFS[3], smem); break;
    }
}

// ---------------------------------------------------------------- k2b: MFMA GEMM out += S * WT^T
__global__ __launch_bounds__(256) void k2b_mfma(
    const char* __restrict__ wsbase, const float* __restrict__ dInv,
    float* __restrict__ out)
{
    const int b = blockIdx.x;
    int pair, mt;
    if (b < 32)       { pair = 0; mt = b; }
    else if (b < 128) { pair = 1; mt = b - 32; }
    else if (b < 160) { pair = 2; mt = b - 128; }
    else              { pair = 3; mt = b - 160; }
    const int U     = (pair == 1 || pair == 3) ? 3 : 1;
    const int dbase = (U == 3) ? 1 : 0;
    const int CKP   = (pair == 3) ? 6208 : 2080;
    const int NK    = CKP >> 5;
    const _Float16* S  = (const _Float16*)(wsbase + S_BYTE) + SOFFS[pair];
    const _Float16* WT = (const _Float16*)wsbase + WTOFFS[pair];

    const int t = threadIdx.x;
    const int wv = t >> 6, l = t & 63;
    const int q = l >> 4, c16 = l & 15;
    const int KC = (NK + 3) >> 2;
    const int k_lo = wv * KC;
    const int k_hi = (k_lo + KC < NK) ? (k_lo + KC) : NK;

    const int row0 = mt * 16;
    const _Float16* sp = S  + (size_t)(row0 + c16) * CKP + q*8;
    const _Float16* wp = WT + (size_t)c16 * CKP + q*8;

    v4f acc; acc[0]=0.f; acc[1]=0.f; acc[2]=0.f; acc[3]=0.f;
    #pragma unroll 4
    for (int ks = k_lo; ks < k_hi; ++ks) {
        const v8h a  = *(const v8h*)(sp + ks*32);
        const v8h bf = *(const v8h*)(wp + ks*32);
        acc = __builtin_amdgcn_mfma_f32_16x16x32_f16(a, bf, acc, 0, 0, 0);
    }

    __shared__ float red[4][16][16];
    #pragma unroll
    for (int r = 0; r < 4; ++r) red[wv][q*4 + r][c16] = acc[r];
    __syncthreads();

    {
        const int r16 = t >> 4, o = t & 15;
        const float v = red[0][r16][o] + red[1][r16][o] + red[2][r16][o] + red[3][r16][o];
        const int row = row0 + r16;
        int n, u;
        if (U == 1) { n = row; u = 0; }
        else        { n = row / 3; u = row - n*3; }
        atomicAdd(out + (size_t)(n*16 + o)*4 + (dbase ? 1 + u : 0), v * dInv[n]);
    }
}

// ---------------------------------------------------------------- launch
extern "C" void kernel_launch(void* const* d_in, const int* in_sizes, int n_in,
                              void* d_out, int out_size, void* d_ws, size_t ws_size,
                              hipStream_t stream)
{
    const float* x0    = (const float*)d_in[0];
    const float* x1    = (const float*)d_in[1];
    const float* rel   = (const float*)d_in[2];
    const int*   nidx  = (const int*)d_in[3];
    const void*  nmask = d_in[4];
    const float* basis[4] = {(const float*)d_in[5], (const float*)d_in[6],
                             (const float*)d_in[7], (const float*)d_in[8]};
    const float* w1  = (const float*)d_in[9];
    const float* b1  = (const float*)d_in[10];
    const float* g1  = (const float*)d_in[11];
    const float* be1 = (const float*)d_in[12];
    const float* w2  = (const float*)d_in[13];
    const float* b2  = (const float*)d_in[14];
    const float* g2  = (const float*)d_in[15];
    const float* be2 = (const float*)d_in[16];
    const float* w3a[4] = {(const float*)d_in[17], (const float*)d_in[19],
                           (const float*)d_in[21], (const float*)d_in[23]};
    const float* b3a[4] = {(const float*)d_in[18], (const float*)d_in[20],
                           (const float*)d_in[22], (const float*)d_in[24]};
    const float* ks0 = (const float*)d_in[25];
    const float* ks1 = (const float*)d_in[26];
    float* out = (float*)d_out;

    char*      ws    = (char*)d_ws;
    _Float16*  WT    = (_Float16*)ws;
    float*     stats = (float*)(ws + ST_BYTE);
    float*     dInv  = (float*)(ws + DI_BYTE);
    _Float16*  w2h   = (_Float16*)(ws + W2H_BYTE);
    _Float16*  h2t0  = (_Float16*)(ws + H2T_BYTE);

    k0_prep<<<1212, 256, 0, stream>>>(w1, b1, nmask, x0, x1, ks0, ks1, w2,
                                      w3a[0], b3a[0], w3a[1], b3a[1],
                                      w3a[2], b3a[2], w3a[3], b3a[3],
                                      dInv, out, stats, WT, w2h, h2t0);

    k1_mfma<<<dim3(384, 4), 256, 0, stream>>>(rel, w1, b1, g1, be1, b2, g2, be2, stats, ws);

    k2a_all<<<2048, 256, 0, stream>>>(x0, x1, nidx, nmask,
                                      basis[0], basis[1], basis[2], basis[3], stats, ws);

    k2b_mfma<<<256, 256, 0, stream>>>(ws, dInv, out);
}